// Round 2
// baseline (552.246 us; speedup 1.0000x reference)
//
#include <hip/hip_runtime.h>
#include <hip/hip_bf16.h>

#define NN 2048
#define DD 512
#define NBATCH 4
#define KNB 10
#define NPAIR 45

// ---------------------------------------------------------------------------
// helpers
// ---------------------------------------------------------------------------
__device__ __forceinline__ float tri_area(float p0x, float p0y, float p0z,
                                          float p1x, float p1y, float p1z,
                                          float p2x, float p2y, float p2z) {
    // mirrors: e1 = p1-p0; e2 = p2-p0; 0.5*||cross(e1,e2)||  (all f32, no fma)
    float e1x = __fsub_rn(p1x, p0x), e1y = __fsub_rn(p1y, p0y), e1z = __fsub_rn(p1z, p0z);
    float e2x = __fsub_rn(p2x, p0x), e2y = __fsub_rn(p2y, p0y), e2z = __fsub_rn(p2z, p0z);
    float c0 = __fsub_rn(__fmul_rn(e1y, e2z), __fmul_rn(e1z, e2y));
    float c1 = __fsub_rn(__fmul_rn(e1z, e2x), __fmul_rn(e1x, e2z));
    float c2 = __fsub_rn(__fmul_rn(e1x, e2y), __fmul_rn(e1y, e2x));
    float ss = __fadd_rn(__fadd_rn(__fmul_rn(c0, c0), __fmul_rn(c1, c1)), __fmul_rn(c2, c2));
    return __fmul_rn(0.5f, sqrtf(ss));
}

// ---------------------------------------------------------------------------
// K0: sq[b][n] = sum(x*x) over the 3 coords
// ---------------------------------------------------------------------------
__global__ __launch_bounds__(256) void compute_sq(const float* __restrict__ srcP,
                                                  float* __restrict__ sq) {
    int i = blockIdx.x * 256 + threadIdx.x;
    if (i >= NBATCH * NN) return;
    int b = i / NN, n = i % NN;
    const float* xs = srcP + (size_t)b * 3 * NN;
    float x0 = xs[n], x1 = xs[NN + n], x2 = xs[2 * NN + n];
    float s = __fadd_rn(__fadd_rn(__fmul_rn(x0, x0), __fmul_rn(x1, x1)), __fmul_rn(x2, x2));
    sq[i] = s;
}

// ---------------------------------------------------------------------------
// K1: scores[n][m] = (sum_d A[d][n]*B[d][m]) / sqrt(512)   per batch
// ---------------------------------------------------------------------------
__global__ __launch_bounds__(256) void gemm_scores(const float* __restrict__ A,
                                                   const float* __restrict__ Bm,
                                                   float* __restrict__ S, int b0) {
    int b = b0 + blockIdx.z;
    const float* Ab = A + (size_t)b * DD * NN;
    const float* Bb = Bm + (size_t)b * DD * NN;
    float* Sb = S + (size_t)blockIdx.z * NN * NN;
    int n0 = blockIdx.y * 64, m0 = blockIdx.x * 64;
    __shared__ float As[16][64];
    __shared__ float Bs[16][64];
    int tid = threadIdx.x;
    int tx = tid & 15, ty = tid >> 4;
    int lc = tid & 63, lr = tid >> 6;  // lr in 0..3
    float acc[4][4] = {{0.f}};
    for (int k0 = 0; k0 < DD; k0 += 16) {
#pragma unroll
        for (int r = 0; r < 4; r++) {
            As[lr + 4 * r][lc] = Ab[(size_t)(k0 + lr + 4 * r) * NN + n0 + lc];
            Bs[lr + 4 * r][lc] = Bb[(size_t)(k0 + lr + 4 * r) * NN + m0 + lc];
        }
        __syncthreads();
#pragma unroll
        for (int kk = 0; kk < 16; kk++) {
            float a[4], bb[4];
#pragma unroll
            for (int i = 0; i < 4; i++) a[i] = As[kk][ty + 16 * i];
#pragma unroll
            for (int j = 0; j < 4; j++) bb[j] = Bs[kk][tx + 16 * j];
#pragma unroll
            for (int i = 0; i < 4; i++)
#pragma unroll
                for (int j = 0; j < 4; j++) acc[i][j] = fmaf(a[i], bb[j], acc[i][j]);
        }
        __syncthreads();
    }
#pragma unroll
    for (int i = 0; i < 4; i++) {
        int n = n0 + ty + 16 * i;
#pragma unroll
        for (int j = 0; j < 4; j++) {
            int m = m0 + tx + 16 * j;
            Sb[(size_t)n * NN + m] = __fdiv_rn(acc[i][j], 22.627416997969522f);
        }
    }
}

// ---------------------------------------------------------------------------
// K2: per-row: argmax (first-occurrence), softmax(10000*s), corr_tgt
// ---------------------------------------------------------------------------
__global__ __launch_bounds__(256) void row_softmax(const float* __restrict__ S,
                                                   const float* __restrict__ tgtP,
                                                   float* __restrict__ corrTgt,
                                                   int* __restrict__ corres, int b0) {
    int zb = blockIdx.y;
    int b = b0 + zb;
    int n = blockIdx.x;
    const float* row = S + (size_t)zb * NN * NN + (size_t)n * NN;
    const float* tb = tgtP + (size_t)b * 3 * NN;
    __shared__ float rv[256];
    __shared__ int ri[256];
    int tid = threadIdx.x;

    float sv[8];
    float bm = -3.4e38f;
    int bi = NN;
#pragma unroll
    for (int r = 0; r < 8; r++) {
        int m = tid + 256 * r;
        float s = __fmul_rn(10000.0f, row[m]);
        sv[r] = s;
        if (s > bm) { bm = s; bi = m; }  // ascending m -> strict > keeps first max
    }
    rv[tid] = bm;
    ri[tid] = bi;
    __syncthreads();
    for (int st = 128; st > 0; st >>= 1) {
        if (tid < st) {
            float ov = rv[tid + st];
            int oi = ri[tid + st];
            if (ov > rv[tid] || (ov == rv[tid] && oi < ri[tid])) { rv[tid] = ov; ri[tid] = oi; }
        }
        __syncthreads();
    }
    float M = rv[0];
    int am = ri[0];
    if (tid == 0) corres[b * NN + n] = am;
    __syncthreads();

    float sloc = 0.f;
#pragma unroll
    for (int r = 0; r < 8; r++) {
        sv[r] = expf(__fsub_rn(sv[r], M));
        sloc = __fadd_rn(sloc, sv[r]);
    }
    rv[tid] = sloc;
    __syncthreads();
    for (int st = 128; st > 0; st >>= 1) {
        if (tid < st) rv[tid] = __fadd_rn(rv[tid], rv[tid + st]);
        __syncthreads();
    }
    float Ssum = rv[0];
    __syncthreads();

    float c[3] = {0.f, 0.f, 0.f};
#pragma unroll
    for (int r = 0; r < 8; r++) {
        int m = tid + 256 * r;
        float p = __fdiv_rn(sv[r], Ssum);
        c[0] = fmaf(p, tb[m], c[0]);
        c[1] = fmaf(p, tb[NN + m], c[1]);
        c[2] = fmaf(p, tb[2 * NN + m], c[2]);
    }
    for (int d = 0; d < 3; d++) {
        rv[tid] = c[d];
        __syncthreads();
        for (int st = 128; st > 0; st >>= 1) {
            if (tid < st) rv[tid] = __fadd_rn(rv[tid], rv[tid + st]);
            __syncthreads();
        }
        if (tid == 0) corrTgt[((size_t)b * NN + n) * 3 + d] = rv[0];
        __syncthreads();
    }
}

// ---------------------------------------------------------------------------
// K3: GFM per anchor point
// ---------------------------------------------------------------------------
__global__ __launch_bounds__(256) void gfm_kernel(const float* __restrict__ srcP,
                                                  const float* __restrict__ corrTgt,
                                                  const float* __restrict__ sq,
                                                  float* __restrict__ pointLoss) {
    int b = blockIdx.y, n = blockIdx.x, tid = threadIdx.x;
    const float* xs = srcP + (size_t)b * 3 * NN;
    __shared__ float wl[NN];
    __shared__ float rv[256];
    __shared__ int ri[256];
    __shared__ int nb[KNB];
    __shared__ float ps[KNB][3], pt[KNB][3];
    __shared__ float lossA[NPAIR], regA[NPAIR], sortedL[NPAIR], tmpL[NPAIR];

    float a0 = xs[n], a1 = xs[NN + n], a2 = xs[2 * NN + n];
    float sqa = sq[b * NN + n];
    for (int m = tid; m < NN; m += 256) {
        float x0 = xs[m], x1 = xs[NN + m], x2 = xs[2 * NN + m];
        float dot = __fadd_rn(__fadd_rn(__fmul_rn(a0, x0), __fmul_rn(a1, x1)), __fmul_rn(a2, x2));
        float d2 = __fsub_rn(__fadd_rn(sqa, sq[b * NN + m]), __fmul_rn(2.0f, dot));
        d2 = fmaxf(d2, 0.0f);
        float dd = sqrtf(d2);
        wl[m] = expf(__fmul_rn(__fmul_rn(-dd, dd), 0.5f));  // -d*d/2
    }
    __syncthreads();

    // top-10 by value desc, index asc (lax.top_k tie semantics)
    for (int it = 0; it < KNB; it++) {
        float bm = -1.f;
        int bi = NN;
        for (int m = tid; m < NN; m += 256) {
            float v = wl[m];
            if (v > bm) { bm = v; bi = m; }
        }
        rv[tid] = bm;
        ri[tid] = bi;
        __syncthreads();
        for (int st = 128; st > 0; st >>= 1) {
            if (tid < st) {
                float ov = rv[tid + st];
                int oi = ri[tid + st];
                if (ov > rv[tid] || (ov == rv[tid] && oi < ri[tid])) { rv[tid] = ov; ri[tid] = oi; }
            }
            __syncthreads();
        }
        if (tid == 0) {
            nb[it] = ri[0];
            wl[ri[0]] = -2.0f;
        }
        __syncthreads();
    }

    if (tid < KNB) {
        int j = nb[tid];
        ps[tid][0] = xs[j];
        ps[tid][1] = xs[NN + j];
        ps[tid][2] = xs[2 * NN + j];
        const float* ct = corrTgt + ((size_t)b * NN + j) * 3;
        pt[tid][0] = ct[0];
        pt[tid][1] = ct[1];
        pt[tid][2] = ct[2];
    }
    __syncthreads();

    if (tid < NPAIR) {
        // decode pair (ja, jb) in combinations(range(10),2) order
        int k = tid, ja = 0, cnt = 9;
        while (k >= cnt) { k -= cnt; ja++; cnt--; }
        int jb = ja + 1 + k;
        const float* ctn = corrTgt + ((size_t)b * NN + n) * 3;
        float area_s = tri_area(a0, a1, a2, ps[ja][0], ps[ja][1], ps[ja][2],
                                ps[jb][0], ps[jb][1], ps[jb][2]);
        float area_t = tri_area(ctn[0], ctn[1], ctn[2], pt[ja][0], pt[ja][1], pt[ja][2],
                                pt[jb][0], pt[jb][1], pt[jb][2]);
        const float EPSF = 1e-6f;
        float ee = __fmul_rn(EPSF, EPSF);
        float lt2 = __fadd_rn(area_t, EPSF);          // lt z-component
        float da = __fsub_rn(area_s, lt2);            // (ls-lt)_z
        float sa = __fadd_rn(area_s, lt2);            // (ls+lt)_z
        float num = __fadd_rn(__fadd_rn(ee, ee), __fmul_rn(da, da));
        float den = __fadd_rn(__fadd_rn(ee, ee), __fmul_rn(sa, sa));
        lossA[tid] = __fdiv_rn(num, den);
        regA[tid] = sqrtf(num);
    }
    __syncthreads();

    if (tid == 0) {
        for (int i = 0; i < NPAIR; i++) sortedL[i] = lossA[i];
        for (int i = 1; i < NPAIR; i++) {  // insertion sort ascending
            float key = sortedL[i];
            int j = i - 1;
            while (j >= 0 && sortedL[j] > key) { sortedL[j + 1] = sortedL[j]; j--; }
            sortedL[j + 1] = key;
        }
        // loss2 = sorted_loss + 0.1*reg  (reg in ORIGINAL pair order)
        for (int i = 0; i < NPAIR; i++) {
            float v = __fadd_rn(sortedL[i], __fmul_rn(0.1f, regA[i]));
            lossA[i] = v;
            tmpL[i] = v;
        }
        for (int i = 1; i < NPAIR; i++) {
            float key = tmpL[i];
            int j = i - 1;
            while (j >= 0 && tmpL[j] > key) { tmpL[j + 1] = tmpL[j]; j--; }
            tmpL[j + 1] = key;
        }
        float med = tmpL[22];  // median of 45
        float thr = __fmul_rn(3.0f, med);
        float sum = 0.f;
        for (int k2 = 0; k2 < KNB; k2++) {
            float v = lossA[k2];
            if (v > thr) v = 0.f;
            sum = __fadd_rn(sum, sqrtf(__fadd_rn(v, 1e-6f)));
        }
        pointLoss[b * NN + n] = __fdiv_rn(sum, 10.0f);
    }
}

// ---------------------------------------------------------------------------
// K4: per-batch min of pointLoss
// ---------------------------------------------------------------------------
__global__ __launch_bounds__(256) void min_kernel(const float* __restrict__ pl,
                                                  float* __restrict__ minL) {
    int b = blockIdx.x, tid = threadIdx.x;
    __shared__ float sd[256];
    float m = 3.4e38f;
    for (int n = tid; n < NN; n += 256) m = fminf(m, pl[b * NN + n]);
    sd[tid] = m;
    __syncthreads();
    for (int st = 128; st > 0; st >>= 1) {
        if (tid < st) sd[tid] = fminf(sd[tid], sd[tid + st]);
        __syncthreads();
    }
    if (tid == 0) minL[b] = sd[0];
}

// ---------------------------------------------------------------------------
// K5: weight + FLOAT32 outputs for corres & weight
// ---------------------------------------------------------------------------
__global__ __launch_bounds__(256) void weight_kernel(const float* __restrict__ pl,
                                                     const float* __restrict__ minL,
                                                     const int* __restrict__ corres,
                                                     float* __restrict__ weight,
                                                     float* __restrict__ outC,
                                                     float* __restrict__ outW) {
    int i = blockIdx.x * 256 + threadIdx.x;
    if (i >= NBATCH * NN) return;
    int b = i / NN;
    float l = __fsub_rn(pl[i], minL[b]);
    float z = __fmul_rn(-20.0f, l);  // z <= 0
    float ez = expf(z);
    float sg = __fdiv_rn(ez, __fadd_rn(1.0f, ez));  // sigmoid for z<=0
    float w2 = __fmul_rn(2.0f, sg);
    float wf = (w2 > 0.5f) ? 1.0f : 0.0f;
    weight[i] = wf;
    outW[i] = wf;
    outC[i] = (float)corres[i];
}

// ---------------------------------------------------------------------------
// K6: per-batch Procrustes reductions (double)
// red[b*16 + 0..8]=Sxy, +9..11=mux, +12..14=muy, +15=W1
// ---------------------------------------------------------------------------
__device__ __forceinline__ double block_red_d(double v, double* sd, int tid) {
    sd[tid] = v;
    __syncthreads();
    for (int st = 128; st > 0; st >>= 1) {
        if (tid < st) sd[tid] += sd[tid + st];
        __syncthreads();
    }
    double r = sd[0];
    __syncthreads();
    return r;
}

__global__ __launch_bounds__(256) void proc_reduce(const float* __restrict__ srcP,
                                                   const float* __restrict__ tgtP,
                                                   const int* __restrict__ corres,
                                                   const float* __restrict__ weight,
                                                   double* __restrict__ red) {
    int b = blockIdx.x, tid = threadIdx.x;
    __shared__ double sd[256];
    const float* xs = srcP + (size_t)b * 3 * NN;
    const float* ts = tgtP + (size_t)b * 3 * NN;
    const int* cr = corres + b * NN;
    const float* wv = weight + b * NN;

    double cw = 0, cx0 = 0, cx1 = 0, cx2 = 0, cy0 = 0, cy1 = 0, cy2 = 0;
    for (int nn2 = tid; nn2 < NN; nn2 += 256) {
        if (wv[nn2] != 0.0f) {
            cw += 1.0;
            cx0 += (double)xs[nn2];
            cx1 += (double)xs[NN + nn2];
            cx2 += (double)xs[2 * NN + nn2];
            int m = cr[nn2];
            cy0 += (double)ts[m];
            cy1 += (double)ts[NN + m];
            cy2 += (double)ts[2 * NN + m];
        }
    }
    double W1 = block_red_d(cw, sd, tid);
    double tx0 = block_red_d(cx0, sd, tid);
    double tx1 = block_red_d(cx1, sd, tid);
    double tx2 = block_red_d(cx2, sd, tid);
    double ty0 = block_red_d(cy0, sd, tid);
    double ty1 = block_red_d(cy1, sd, tid);
    double ty2 = block_red_d(cy2, sd, tid);
    double W1e = W1 + 1e-7;
    double mux0 = tx0 / W1e, mux1 = tx1 / W1e, mux2 = tx2 / W1e;
    double muy0 = ty0 / W1e, muy1 = ty1 / W1e, muy2 = ty2 / W1e;

    double s[9] = {0, 0, 0, 0, 0, 0, 0, 0, 0};
    for (int nn2 = tid; nn2 < NN; nn2 += 256) {
        if (wv[nn2] != 0.0f) {
            double dx0 = (double)xs[nn2] - mux0;
            double dx1 = (double)xs[NN + nn2] - mux1;
            double dx2 = (double)xs[2 * NN + nn2] - mux2;
            int m = cr[nn2];
            double dy0 = (double)ts[m] - muy0;
            double dy1 = (double)ts[NN + m] - muy1;
            double dy2 = (double)ts[2 * NN + m] - muy2;
            s[0] += dy0 * dx0; s[1] += dy0 * dx1; s[2] += dy0 * dx2;
            s[3] += dy1 * dx0; s[4] += dy1 * dx1; s[5] += dy1 * dx2;
            s[6] += dy2 * dx0; s[7] += dy2 * dx1; s[8] += dy2 * dx2;
        }
    }
#pragma unroll
    for (int k = 0; k < 9; k++) {
        double tot = block_red_d(s[k], sd, tid);
        if (tid == 0) red[b * 16 + k] = tot / W1e;
    }
    if (tid == 0) {
        red[b * 16 + 9] = mux0; red[b * 16 + 10] = mux1; red[b * 16 + 11] = mux2;
        red[b * 16 + 12] = muy0; red[b * 16 + 13] = muy1; red[b * 16 + 14] = muy2;
        red[b * 16 + 15] = W1e;
    }
}

// ---------------------------------------------------------------------------
// K7: 3x3 SVD (one-sided Jacobi, f64) -> R, T   (FLOAT32 outputs)
// ---------------------------------------------------------------------------
__device__ double det3(const double M[3][3]) {
    return M[0][0] * (M[1][1] * M[2][2] - M[1][2] * M[2][1]) -
           M[0][1] * (M[1][0] * M[2][2] - M[1][2] * M[2][0]) +
           M[0][2] * (M[1][0] * M[2][1] - M[1][1] * M[2][0]);
}

__global__ void svd_finalize(const double* __restrict__ red,
                             float* __restrict__ outR,
                             float* __restrict__ outT) {
    int b = threadIdx.x;
    if (b >= NBATCH) return;
    double A[3][3], Bm[3][3], V[3][3];
    for (int r = 0; r < 3; r++)
        for (int c2 = 0; c2 < 3; c2++) {
            A[r][c2] = red[b * 16 + r * 3 + c2];
            Bm[r][c2] = A[r][c2];
            V[r][c2] = (r == c2) ? 1.0 : 0.0;
        }
    double nrm2 = 0;
    for (int r = 0; r < 3; r++)
        for (int c2 = 0; c2 < 3; c2++) nrm2 += Bm[r][c2] * Bm[r][c2];

    for (int sweep = 0; sweep < 60; sweep++) {
        double off = 0;
        for (int p = 0; p < 2; p++) {
            for (int q = p + 1; q < 3; q++) {
                double al = 0, be = 0, ga = 0;
                for (int i = 0; i < 3; i++) {
                    al += Bm[i][p] * Bm[i][p];
                    be += Bm[i][q] * Bm[i][q];
                    ga += Bm[i][p] * Bm[i][q];
                }
                off += ga * ga;
                if (fabs(ga) > 1e-300) {
                    double ze = (be - al) / (2.0 * ga);
                    double t = copysign(1.0, ze) / (fabs(ze) + sqrt(1.0 + ze * ze));
                    double c = 1.0 / sqrt(1.0 + t * t), sn = c * t;
                    for (int i = 0; i < 3; i++) {
                        double bp = Bm[i][p], bq = Bm[i][q];
                        Bm[i][p] = c * bp - sn * bq;
                        Bm[i][q] = sn * bp + c * bq;
                        double vp = V[i][p], vq = V[i][q];
                        V[i][p] = c * vp - sn * vq;
                        V[i][q] = sn * vp + c * vq;
                    }
                }
            }
        }
        if (off <= 1e-30 * nrm2 * nrm2) break;
    }
    double sig[3];
    for (int j = 0; j < 3; j++) {
        double ss = 0;
        for (int i = 0; i < 3; i++) ss += Bm[i][j] * Bm[i][j];
        sig[j] = sqrt(ss);
    }
    // sort columns by sigma descending
    for (int a = 0; a < 2; a++)
        for (int j = 0; j < 2 - a; j++)
            if (sig[j] < sig[j + 1]) {
                double t = sig[j]; sig[j] = sig[j + 1]; sig[j + 1] = t;
                for (int i = 0; i < 3; i++) {
                    double tb = Bm[i][j]; Bm[i][j] = Bm[i][j + 1]; Bm[i][j + 1] = tb;
                    double tv = V[i][j]; V[i][j] = V[i][j + 1]; V[i][j + 1] = tv;
                }
            }
    double U[3][3];
    for (int j = 0; j < 3; j++) {
        double inv = (sig[j] > 1e-150) ? 1.0 / sig[j] : 0.0;
        for (int i = 0; i < 3; i++) U[i][j] = Bm[i][j] * inv;
    }
    if (sig[2] <= 1e-10 * (sig[0] + 1e-300)) {  // complete degenerate 3rd col
        double u0 = U[1][0] * U[2][1] - U[2][0] * U[1][1];
        double u1 = U[2][0] * U[0][1] - U[0][0] * U[2][1];
        double u2 = U[0][0] * U[1][1] - U[1][0] * U[0][1];
        double nr = sqrt(u0 * u0 + u1 * u1 + u2 * u2);
        if (nr > 1e-150) { U[0][2] = u0 / nr; U[1][2] = u1 / nr; U[2][2] = u2 / nr; }
    }
    double dU = det3(U), dV = det3(V);
    double s3 = (dU * dV >= 0.0) ? 1.0 : -1.0;
    double R[3][3];
    for (int i = 0; i < 3; i++)
        for (int j = 0; j < 3; j++)
            R[i][j] = U[i][0] * V[j][0] + U[i][1] * V[j][1] + s3 * U[i][2] * V[j][2];
    double mux[3] = {red[b * 16 + 9], red[b * 16 + 10], red[b * 16 + 11]};
    double muy[3] = {red[b * 16 + 12], red[b * 16 + 13], red[b * 16 + 14]};
    for (int i = 0; i < 3; i++) {
        for (int j = 0; j < 3; j++) outR[b * 9 + i * 3 + j] = (float)R[i][j];
        double t = muy[i] - (R[i][0] * mux[0] + R[i][1] * mux[1] + R[i][2] * mux[2]);
        outT[b * 3 + i] = (float)t;
    }
}

// ---------------------------------------------------------------------------
// host launcher
// ---------------------------------------------------------------------------
extern "C" void kernel_launch(void* const* d_in, const int* in_sizes, int n_in,
                              void* d_out, int out_size, void* d_ws, size_t ws_size,
                              hipStream_t stream) {
    const float* srcE = (const float*)d_in[0];
    const float* tgtE = (const float*)d_in[1];
    const float* srcP = (const float*)d_in[2];
    const float* tgtP = (const float*)d_in[3];
    float* out = (float*)d_out;  // f32 outputs: R[36] T[12] corres[8192] weight[8192]

    char* w = (char*)d_ws;
    size_t off = 0;
    auto alloc = [&](size_t bytes) -> void* {
        void* p = w + off;
        off = (off + bytes + 255) & ~(size_t)255;
        return p;
    };
    float* corrTgt = (float*)alloc((size_t)NBATCH * NN * 3 * 4);
    int* corres = (int*)alloc((size_t)NBATCH * NN * 4);
    float* sq = (float*)alloc((size_t)NBATCH * NN * 4);
    float* pointLoss = (float*)alloc((size_t)NBATCH * NN * 4);
    float* minL = (float*)alloc(NBATCH * 4);
    float* weight = (float*)alloc((size_t)NBATCH * NN * 4);
    double* red = (double*)alloc(NBATCH * 16 * 8);
    size_t fixed = off;
    int nb = (ws_size >= fixed + (size_t)NBATCH * NN * NN * 4) ? NBATCH : 1;
    float* scores = (float*)alloc((size_t)nb * NN * NN * 4);

    compute_sq<<<(NBATCH * NN + 255) / 256, 256, 0, stream>>>(srcP, sq);

    for (int b0 = 0; b0 < NBATCH; b0 += nb) {
        gemm_scores<<<dim3(NN / 64, NN / 64, nb), 256, 0, stream>>>(srcE, tgtE, scores, b0);
        row_softmax<<<dim3(NN, nb), 256, 0, stream>>>(scores, tgtP, corrTgt, corres, b0);
    }

    gfm_kernel<<<dim3(NN, NBATCH), 256, 0, stream>>>(srcP, corrTgt, sq, pointLoss);
    min_kernel<<<NBATCH, 256, 0, stream>>>(pointLoss, minL);
    weight_kernel<<<(NBATCH * NN + 255) / 256, 256, 0, stream>>>(
        pointLoss, minL, corres, weight, out + 48, out + 48 + NBATCH * NN);
    proc_reduce<<<NBATCH, 256, 0, stream>>>(srcP, tgtP, corres, weight, red);
    svd_finalize<<<1, 64, 0, stream>>>(red, out, out + 36);
}

// Round 3
// 253.810 us; speedup vs baseline: 2.1758x; 2.1758x over previous
//
#include <hip/hip_runtime.h>
#include <hip/hip_bf16.h>

#define NN 2048
#define DD 512
#define NBATCH 4
#define KNB 10
#define NPAIR 45

typedef __attribute__((ext_vector_type(8))) short bf16x8;
typedef __attribute__((ext_vector_type(4))) float f32x4;

// ---------------------------------------------------------------------------
// helpers
// ---------------------------------------------------------------------------
__device__ __forceinline__ float tri_area(float p0x, float p0y, float p0z,
                                          float p1x, float p1y, float p1z,
                                          float p2x, float p2y, float p2z) {
    float e1x = __fsub_rn(p1x, p0x), e1y = __fsub_rn(p1y, p0y), e1z = __fsub_rn(p1z, p0z);
    float e2x = __fsub_rn(p2x, p0x), e2y = __fsub_rn(p2y, p0y), e2z = __fsub_rn(p2z, p0z);
    float c0 = __fsub_rn(__fmul_rn(e1y, e2z), __fmul_rn(e1z, e2y));
    float c1 = __fsub_rn(__fmul_rn(e1z, e2x), __fmul_rn(e1x, e2z));
    float c2 = __fsub_rn(__fmul_rn(e1x, e2y), __fmul_rn(e1y, e2x));
    float ss = __fadd_rn(__fadd_rn(__fmul_rn(c0, c0), __fmul_rn(c1, c1)), __fmul_rn(c2, c2));
    return __fmul_rn(0.5f, sqrtf(ss));
}

// ---------------------------------------------------------------------------
// K0: sq[b][n] = sum(x*x)
// ---------------------------------------------------------------------------
__global__ __launch_bounds__(256) void compute_sq(const float* __restrict__ srcP,
                                                  float* __restrict__ sq) {
    int i = blockIdx.x * 256 + threadIdx.x;
    if (i >= NBATCH * NN) return;
    int b = i / NN, n = i % NN;
    const float* xs = srcP + (size_t)b * 3 * NN;
    float x0 = xs[n], x1 = xs[NN + n], x2 = xs[2 * NN + n];
    sq[i] = __fadd_rn(__fadd_rn(__fmul_rn(x0, x0), __fmul_rn(x1, x1)), __fmul_rn(x2, x2));
}

// ---------------------------------------------------------------------------
// K1: MFMA bf16x6 split-precision GEMM.
// scores[n][m] = (sum_d A[d][n]*B[d][m]) / sqrt(512)
// 128x128 tile, BK=32, 256 threads (4 waves, 2x2 of 64x64), in-kernel f32->3xbf16.
// LDS layout per plane: [row 0..127][k 0..31] bf16, 16B-granule XOR swizzle:
//   idx(r,k) = r*32 + ((k>>3 ^ ((r>>1)&3))<<3) + (k&7)
// ---------------------------------------------------------------------------
__global__ __launch_bounds__(256) void gemm_scores_mfma(const float* __restrict__ A,
                                                        const float* __restrict__ Bm,
                                                        float* __restrict__ S, int b0) {
    int b = b0 + blockIdx.z;
    const float* Ab = A + (size_t)b * DD * NN;
    const float* Bb = Bm + (size_t)b * DD * NN;
    float* Sb = S + (size_t)blockIdx.z * NN * NN;
    int n0 = blockIdx.y * 128, m0 = blockIdx.x * 128;

    __shared__ short As[3][128 * 32];
    __shared__ short Bs[3][128 * 32];

    int t = threadIdx.x;
    int w = t >> 6, lane = t & 63;
    int wr = w >> 1, wc = w & 1;           // wave tile (64x64) position
    int fr = lane & 15, kq = lane >> 4;    // fragment row, k-quarter

    // staging assignment: threads 0..127 -> A, 128..255 -> B; rr = row/col in tile
    int rr = t & 127;
    const float* gp;
    short *PH, *PM, *PL;
    if (t < 128) {
        gp = Ab + n0 + rr;
        PH = &As[0][0]; PM = &As[1][0]; PL = &As[2][0];
    } else {
        gp = Bb + m0 + rr;
        PH = &Bs[0][0]; PM = &Bs[1][0]; PL = &Bs[2][0];
    }

    f32x4 acc[4][4];
#pragma unroll
    for (int i = 0; i < 4; i++)
#pragma unroll
        for (int j = 0; j < 4; j++) acc[i][j] = (f32x4){0.f, 0.f, 0.f, 0.f};

    for (int k0 = 0; k0 < DD; k0 += 32) {
        __syncthreads();  // protect previous iteration's fragment reads
#pragma unroll
        for (int kk = 0; kk < 32; kk += 2) {
            float x0 = gp[(size_t)(k0 + kk) * NN];
            float x1 = gp[(size_t)(k0 + kk + 1) * NN];
            unsigned hp, mp, lp;
            asm("v_cvt_pk_bf16_f32 %0, %1, %2" : "=v"(hp) : "v"(x0), "v"(x1));
            float h0 = __uint_as_float(hp << 16);
            float h1 = __uint_as_float(hp & 0xffff0000u);
            float r0 = __fsub_rn(x0, h0), r1 = __fsub_rn(x1, h1);
            asm("v_cvt_pk_bf16_f32 %0, %1, %2" : "=v"(mp) : "v"(r0), "v"(r1));
            float m0f = __uint_as_float(mp << 16);
            float m1f = __uint_as_float(mp & 0xffff0000u);
            float s0 = __fsub_rn(r0, m0f), s1 = __fsub_rn(r1, m1f);
            asm("v_cvt_pk_bf16_f32 %0, %1, %2" : "=v"(lp) : "v"(s0), "v"(s1));
            int bi = (rr * 32 + ((((kk >> 3) ^ ((rr >> 1) & 3))) << 3) + (kk & 7)) >> 1;
            ((unsigned*)PH)[bi] = hp;
            ((unsigned*)PM)[bi] = mp;
            ((unsigned*)PL)[bi] = lp;
        }
        __syncthreads();

        // load fragments: 3 planes x 4 tiles for A (rows) and B (cols)
        bf16x8 ah[4], am_[4], al[4], bh[4], bm_[4], bl[4];
#pragma unroll
        for (int i = 0; i < 4; i++) {
            int rA = wr * 64 + i * 16 + fr;
            int offA = rA * 32 + ((kq ^ ((rA >> 1) & 3)) << 3);
            ah[i] = *(const bf16x8*)&As[0][offA];
            am_[i] = *(const bf16x8*)&As[1][offA];
            al[i] = *(const bf16x8*)&As[2][offA];
            int rB = wc * 64 + i * 16 + fr;
            int offB = rB * 32 + ((kq ^ ((rB >> 1) & 3)) << 3);
            bh[i] = *(const bf16x8*)&Bs[0][offB];
            bm_[i] = *(const bf16x8*)&Bs[1][offB];
            bl[i] = *(const bf16x8*)&Bs[2][offB];
        }
#pragma unroll
        for (int i = 0; i < 4; i++)
#pragma unroll
            for (int j = 0; j < 4; j++) {
                f32x4 c = acc[i][j];
                c = __builtin_amdgcn_mfma_f32_16x16x32_bf16(ah[i], bh[j], c, 0, 0, 0);
                c = __builtin_amdgcn_mfma_f32_16x16x32_bf16(ah[i], bm_[j], c, 0, 0, 0);
                c = __builtin_amdgcn_mfma_f32_16x16x32_bf16(am_[i], bh[j], c, 0, 0, 0);
                c = __builtin_amdgcn_mfma_f32_16x16x32_bf16(am_[i], bm_[j], c, 0, 0, 0);
                c = __builtin_amdgcn_mfma_f32_16x16x32_bf16(ah[i], bl[j], c, 0, 0, 0);
                c = __builtin_amdgcn_mfma_f32_16x16x32_bf16(al[i], bh[j], c, 0, 0, 0);
                acc[i][j] = c;
            }
    }

    // epilogue: /sqrt(512), store
#pragma unroll
    for (int i = 0; i < 4; i++) {
        int crow = n0 + wr * 64 + i * 16 + kq * 4;
#pragma unroll
        for (int j = 0; j < 4; j++) {
            int ccol = m0 + wc * 64 + j * 16 + fr;
#pragma unroll
            for (int rg = 0; rg < 4; rg++) {
                Sb[(size_t)(crow + rg) * NN + ccol] =
                    __fdiv_rn(acc[i][j][rg], 22.627416997969522f);
            }
        }
    }
}

// ---------------------------------------------------------------------------
// K2: wave-per-row argmax + softmax + corr_tgt (shuffle-only, no barriers)
// ---------------------------------------------------------------------------
__global__ __launch_bounds__(256) void row_softmax(const float* __restrict__ S,
                                                   const float* __restrict__ tgtP,
                                                   float* __restrict__ corrTgt,
                                                   int* __restrict__ corres, int b0) {
    int zb = blockIdx.y;
    int b = b0 + zb;
    int w = threadIdx.x >> 6, lane = threadIdx.x & 63;
    int n = blockIdx.x * 4 + w;
    const float* row = S + (size_t)zb * NN * NN + (size_t)n * NN;
    const float* tb = tgtP + (size_t)b * 3 * NN;

    // pass 1: max + first-argmax of sv = 10000*s
    float bm = -3.4e38f;
    int bi = 0x7fffffff;
#pragma unroll
    for (int c = 0; c < 8; c++) {
        int m = c * 256 + lane * 4;
        float4 v = *(const float4*)&row[m];
        float s0 = __fmul_rn(10000.0f, v.x);
        float s1 = __fmul_rn(10000.0f, v.y);
        float s2 = __fmul_rn(10000.0f, v.z);
        float s3 = __fmul_rn(10000.0f, v.w);
        if (s0 > bm) { bm = s0; bi = m; }
        if (s1 > bm) { bm = s1; bi = m + 1; }
        if (s2 > bm) { bm = s2; bi = m + 2; }
        if (s3 > bm) { bm = s3; bi = m + 3; }
    }
#pragma unroll
    for (int st = 1; st < 64; st <<= 1) {
        float ov = __shfl_xor(bm, st, 64);
        int oi = __shfl_xor(bi, st, 64);
        if (ov > bm || (ov == bm && oi < bi)) { bm = ov; bi = oi; }
    }
    // pass 2: esum and weighted tgt (skip exp for underflowing terms — exact)
    float esum = 0.f, c0 = 0.f, c1 = 0.f, c2 = 0.f;
#pragma unroll
    for (int c = 0; c < 8; c++) {
        int m = c * 256 + lane * 4;
        float4 v = *(const float4*)&row[m];
        float sv[4] = {__fmul_rn(10000.0f, v.x), __fmul_rn(10000.0f, v.y),
                       __fmul_rn(10000.0f, v.z), __fmul_rn(10000.0f, v.w)};
#pragma unroll
        for (int q = 0; q < 4; q++) {
            float d = __fsub_rn(sv[q], bm);
            if (d >= -90.0f) {
                float e = expf(d);
                esum = __fadd_rn(esum, e);
                int mi = m + q;
                c0 = fmaf(e, tb[mi], c0);
                c1 = fmaf(e, tb[NN + mi], c1);
                c2 = fmaf(e, tb[2 * NN + mi], c2);
            }
        }
    }
#pragma unroll
    for (int st = 1; st < 64; st <<= 1) {
        esum += __shfl_xor(esum, st, 64);
        c0 += __shfl_xor(c0, st, 64);
        c1 += __shfl_xor(c1, st, 64);
        c2 += __shfl_xor(c2, st, 64);
    }
    if (lane == 0) {
        corres[b * NN + n] = bi;
        size_t o = ((size_t)b * NN + n) * 3;
        corrTgt[o + 0] = __fdiv_rn(c0, esum);
        corrTgt[o + 1] = __fdiv_rn(c1, esum);
        corrTgt[o + 2] = __fdiv_rn(c2, esum);
    }
}

// ---------------------------------------------------------------------------
// K3: GFM per anchor point (register top-k + shuffle + parallel rank sort)
// ---------------------------------------------------------------------------
__global__ __launch_bounds__(256) void gfm_kernel(const float* __restrict__ srcP,
                                                  const float* __restrict__ corrTgt,
                                                  const float* __restrict__ sq,
                                                  float* __restrict__ pointLoss) {
    int b = blockIdx.y, n = blockIdx.x, tid = threadIdx.x;
    int w = tid >> 6, lane = tid & 63;
    const float* xs = srcP + (size_t)b * 3 * NN;
    __shared__ float wv4[4];
    __shared__ int wi4[4];
    __shared__ int nbIdx[KNB];
    __shared__ float ps[KNB][3], pt[KNB][3];
    __shared__ float lossA[NPAIR], regA[NPAIR], sorted1[NPAIR], loss2[NPAIR], sorted2[NPAIR];

    float a0 = xs[n], a1 = xs[NN + n], a2 = xs[2 * NN + n];
    float sqa = sq[b * NN + n];
    float v[8];
#pragma unroll
    for (int r = 0; r < 8; r++) {
        int m = tid + 256 * r;
        float x0 = xs[m], x1 = xs[NN + m], x2 = xs[2 * NN + m];
        float dot = __fadd_rn(__fadd_rn(__fmul_rn(a0, x0), __fmul_rn(a1, x1)), __fmul_rn(a2, x2));
        float d2 = __fsub_rn(__fadd_rn(sqa, sq[b * NN + m]), __fmul_rn(2.0f, dot));
        d2 = fmaxf(d2, 0.0f);
        float dd = sqrtf(d2);
        v[r] = expf(__fmul_rn(__fmul_rn(-dd, dd), 0.5f));
    }

    for (int it = 0; it < KNB; it++) {
        float lm = -10.f;
        int li = 0x7fffffff;
#pragma unroll
        for (int r = 0; r < 8; r++)
            if (v[r] > lm) { lm = v[r]; li = tid + 256 * r; }
#pragma unroll
        for (int st = 1; st < 64; st <<= 1) {
            float ov = __shfl_xor(lm, st, 64);
            int oi = __shfl_xor(li, st, 64);
            if (ov > lm || (ov == lm && oi < li)) { lm = ov; li = oi; }
        }
        if (lane == 0) { wv4[w] = lm; wi4[w] = li; }
        __syncthreads();
        float Vb = wv4[0];
        int Ib = wi4[0];
#pragma unroll
        for (int q = 1; q < 4; q++) {
            float ov = wv4[q];
            int oi = wi4[q];
            if (ov > Vb || (ov == Vb && oi < Ib)) { Vb = ov; Ib = oi; }
        }
        if (tid == (Ib & 255)) v[Ib >> 8] = -10.f;
        if (tid == 0) nbIdx[it] = Ib;
        __syncthreads();
    }

    if (tid < KNB) {
        int j = nbIdx[tid];
        ps[tid][0] = xs[j];
        ps[tid][1] = xs[NN + j];
        ps[tid][2] = xs[2 * NN + j];
        const float* ct = corrTgt + ((size_t)b * NN + j) * 3;
        pt[tid][0] = ct[0];
        pt[tid][1] = ct[1];
        pt[tid][2] = ct[2];
    }
    __syncthreads();

    if (tid < NPAIR) {
        int k = tid, ja = 0, cnt = 9;
        while (k >= cnt) { k -= cnt; ja++; cnt--; }
        int jb = ja + 1 + k;
        const float* ctn = corrTgt + ((size_t)b * NN + n) * 3;
        float area_s = tri_area(a0, a1, a2, ps[ja][0], ps[ja][1], ps[ja][2],
                                ps[jb][0], ps[jb][1], ps[jb][2]);
        float area_t = tri_area(ctn[0], ctn[1], ctn[2], pt[ja][0], pt[ja][1], pt[ja][2],
                                pt[jb][0], pt[jb][1], pt[jb][2]);
        const float EPSF = 1e-6f;
        float ee = __fmul_rn(EPSF, EPSF);
        float lt2 = __fadd_rn(area_t, EPSF);
        float da = __fsub_rn(area_s, lt2);
        float sa = __fadd_rn(area_s, lt2);
        float num = __fadd_rn(__fadd_rn(ee, ee), __fmul_rn(da, da));
        float den = __fadd_rn(__fadd_rn(ee, ee), __fmul_rn(sa, sa));
        lossA[tid] = __fdiv_rn(num, den);
        regA[tid] = sqrtf(num);
    }
    __syncthreads();

    if (tid < NPAIR) {  // rank sort #1 (stable)
        float x = lossA[tid];
        int rk = 0;
#pragma unroll 9
        for (int j = 0; j < NPAIR; j++) {
            float y = lossA[j];
            rk += (y < x || (y == x && j < tid)) ? 1 : 0;
        }
        sorted1[rk] = x;
    }
    __syncthreads();
    if (tid < NPAIR) loss2[tid] = __fadd_rn(sorted1[tid], __fmul_rn(0.1f, regA[tid]));
    __syncthreads();
    if (tid < NPAIR) {  // rank sort #2
        float x = loss2[tid];
        int rk = 0;
#pragma unroll 9
        for (int j = 0; j < NPAIR; j++) {
            float y = loss2[j];
            rk += (y < x || (y == x && j < tid)) ? 1 : 0;
        }
        sorted2[rk] = x;
    }
    __syncthreads();
    if (tid == 0) {
        float med = sorted2[22];
        float thr = __fmul_rn(3.0f, med);
        float sum = 0.f;
        for (int k2 = 0; k2 < KNB; k2++) {
            float vv = loss2[k2];
            if (vv > thr) vv = 0.f;
            sum = __fadd_rn(sum, sqrtf(__fadd_rn(vv, 1e-6f)));
        }
        pointLoss[b * NN + n] = __fdiv_rn(sum, 10.0f);
    }
}

// ---------------------------------------------------------------------------
// K4: per-batch min of pointLoss
// ---------------------------------------------------------------------------
__global__ __launch_bounds__(256) void min_kernel(const float* __restrict__ pl,
                                                  float* __restrict__ minL) {
    int b = blockIdx.x, tid = threadIdx.x;
    __shared__ float sd[256];
    float m = 3.4e38f;
    for (int n = tid; n < NN; n += 256) m = fminf(m, pl[b * NN + n]);
    sd[tid] = m;
    __syncthreads();
    for (int st = 128; st > 0; st >>= 1) {
        if (tid < st) sd[tid] = fminf(sd[tid], sd[tid + st]);
        __syncthreads();
    }
    if (tid == 0) minL[b] = sd[0];
}

// ---------------------------------------------------------------------------
// K5: weight + f32 outputs for corres & weight
// ---------------------------------------------------------------------------
__global__ __launch_bounds__(256) void weight_kernel(const float* __restrict__ pl,
                                                     const float* __restrict__ minL,
                                                     const int* __restrict__ corres,
                                                     float* __restrict__ weight,
                                                     float* __restrict__ outC,
                                                     float* __restrict__ outW) {
    int i = blockIdx.x * 256 + threadIdx.x;
    if (i >= NBATCH * NN) return;
    int b = i / NN;
    float l = __fsub_rn(pl[i], minL[b]);
    float z = __fmul_rn(-20.0f, l);
    float ez = expf(z);
    float sg = __fdiv_rn(ez, __fadd_rn(1.0f, ez));
    float w2 = __fmul_rn(2.0f, sg);
    float wf = (w2 > 0.5f) ? 1.0f : 0.0f;
    weight[i] = wf;
    outW[i] = wf;
    outC[i] = (float)corres[i];
}

// ---------------------------------------------------------------------------
// K6: per-batch Procrustes reductions (double)
// ---------------------------------------------------------------------------
__device__ __forceinline__ double block_red_d(double v, double* sd, int tid) {
    sd[tid] = v;
    __syncthreads();
    for (int st = 128; st > 0; st >>= 1) {
        if (tid < st) sd[tid] += sd[tid + st];
        __syncthreads();
    }
    double r = sd[0];
    __syncthreads();
    return r;
}

__global__ __launch_bounds__(256) void proc_reduce(const float* __restrict__ srcP,
                                                   const float* __restrict__ tgtP,
                                                   const int* __restrict__ corres,
                                                   const float* __restrict__ weight,
                                                   double* __restrict__ red) {
    int b = blockIdx.x, tid = threadIdx.x;
    __shared__ double sd[256];
    const float* xs = srcP + (size_t)b * 3 * NN;
    const float* ts = tgtP + (size_t)b * 3 * NN;
    const int* cr = corres + b * NN;
    const float* wv = weight + b * NN;

    double cw = 0, cx0 = 0, cx1 = 0, cx2 = 0, cy0 = 0, cy1 = 0, cy2 = 0;
    for (int nn2 = tid; nn2 < NN; nn2 += 256) {
        if (wv[nn2] != 0.0f) {
            cw += 1.0;
            cx0 += (double)xs[nn2];
            cx1 += (double)xs[NN + nn2];
            cx2 += (double)xs[2 * NN + nn2];
            int m = cr[nn2];
            cy0 += (double)ts[m];
            cy1 += (double)ts[NN + m];
            cy2 += (double)ts[2 * NN + m];
        }
    }
    double W1 = block_red_d(cw, sd, tid);
    double tx0 = block_red_d(cx0, sd, tid);
    double tx1 = block_red_d(cx1, sd, tid);
    double tx2 = block_red_d(cx2, sd, tid);
    double ty0 = block_red_d(cy0, sd, tid);
    double ty1 = block_red_d(cy1, sd, tid);
    double ty2 = block_red_d(cy2, sd, tid);
    double W1e = W1 + 1e-7;
    double mux0 = tx0 / W1e, mux1 = tx1 / W1e, mux2 = tx2 / W1e;
    double muy0 = ty0 / W1e, muy1 = ty1 / W1e, muy2 = ty2 / W1e;

    double s[9] = {0, 0, 0, 0, 0, 0, 0, 0, 0};
    for (int nn2 = tid; nn2 < NN; nn2 += 256) {
        if (wv[nn2] != 0.0f) {
            double dx0 = (double)xs[nn2] - mux0;
            double dx1 = (double)xs[NN + nn2] - mux1;
            double dx2 = (double)xs[2 * NN + nn2] - mux2;
            int m = cr[nn2];
            double dy0 = (double)ts[m] - muy0;
            double dy1 = (double)ts[NN + m] - muy1;
            double dy2 = (double)ts[2 * NN + m] - muy2;
            s[0] += dy0 * dx0; s[1] += dy0 * dx1; s[2] += dy0 * dx2;
            s[3] += dy1 * dx0; s[4] += dy1 * dx1; s[5] += dy1 * dx2;
            s[6] += dy2 * dx0; s[7] += dy2 * dx1; s[8] += dy2 * dx2;
        }
    }
#pragma unroll
    for (int k = 0; k < 9; k++) {
        double tot = block_red_d(s[k], sd, tid);
        if (tid == 0) red[b * 16 + k] = tot / W1e;
    }
    if (tid == 0) {
        red[b * 16 + 9] = mux0; red[b * 16 + 10] = mux1; red[b * 16 + 11] = mux2;
        red[b * 16 + 12] = muy0; red[b * 16 + 13] = muy1; red[b * 16 + 14] = muy2;
        red[b * 16 + 15] = W1e;
    }
}

// ---------------------------------------------------------------------------
// K7: 3x3 SVD (one-sided Jacobi, f64) -> R, T
// ---------------------------------------------------------------------------
__device__ double det3(const double M[3][3]) {
    return M[0][0] * (M[1][1] * M[2][2] - M[1][2] * M[2][1]) -
           M[0][1] * (M[1][0] * M[2][2] - M[1][2] * M[2][0]) +
           M[0][2] * (M[1][0] * M[2][1] - M[1][1] * M[2][0]);
}

__global__ void svd_finalize(const double* __restrict__ red,
                             float* __restrict__ outR,
                             float* __restrict__ outT) {
    int b = threadIdx.x;
    if (b >= NBATCH) return;
    double A[3][3], Bm[3][3], V[3][3];
    for (int r = 0; r < 3; r++)
        for (int c2 = 0; c2 < 3; c2++) {
            A[r][c2] = red[b * 16 + r * 3 + c2];
            Bm[r][c2] = A[r][c2];
            V[r][c2] = (r == c2) ? 1.0 : 0.0;
        }
    double nrm2 = 0;
    for (int r = 0; r < 3; r++)
        for (int c2 = 0; c2 < 3; c2++) nrm2 += Bm[r][c2] * Bm[r][c2];

    for (int sweep = 0; sweep < 60; sweep++) {
        double off = 0;
        for (int p = 0; p < 2; p++) {
            for (int q = p + 1; q < 3; q++) {
                double al = 0, be = 0, ga = 0;
                for (int i = 0; i < 3; i++) {
                    al += Bm[i][p] * Bm[i][p];
                    be += Bm[i][q] * Bm[i][q];
                    ga += Bm[i][p] * Bm[i][q];
                }
                off += ga * ga;
                if (fabs(ga) > 1e-300) {
                    double ze = (be - al) / (2.0 * ga);
                    double t = copysign(1.0, ze) / (fabs(ze) + sqrt(1.0 + ze * ze));
                    double c = 1.0 / sqrt(1.0 + t * t), sn = c * t;
                    for (int i = 0; i < 3; i++) {
                        double bp = Bm[i][p], bq = Bm[i][q];
                        Bm[i][p] = c * bp - sn * bq;
                        Bm[i][q] = sn * bp + c * bq;
                        double vp = V[i][p], vq = V[i][q];
                        V[i][p] = c * vp - sn * vq;
                        V[i][q] = sn * vp + c * vq;
                    }
                }
            }
        }
        if (off <= 1e-30 * nrm2 * nrm2) break;
    }
    double sig[3];
    for (int j = 0; j < 3; j++) {
        double ss = 0;
        for (int i = 0; i < 3; i++) ss += Bm[i][j] * Bm[i][j];
        sig[j] = sqrt(ss);
    }
    for (int a = 0; a < 2; a++)
        for (int j = 0; j < 2 - a; j++)
            if (sig[j] < sig[j + 1]) {
                double t = sig[j]; sig[j] = sig[j + 1]; sig[j + 1] = t;
                for (int i = 0; i < 3; i++) {
                    double tb = Bm[i][j]; Bm[i][j] = Bm[i][j + 1]; Bm[i][j + 1] = tb;
                    double tv = V[i][j]; V[i][j] = V[i][j + 1]; V[i][j + 1] = tv;
                }
            }
    double U[3][3];
    for (int j = 0; j < 3; j++) {
        double inv = (sig[j] > 1e-150) ? 1.0 / sig[j] : 0.0;
        for (int i = 0; i < 3; i++) U[i][j] = Bm[i][j] * inv;
    }
    if (sig[2] <= 1e-10 * (sig[0] + 1e-300)) {
        double u0 = U[1][0] * U[2][1] - U[2][0] * U[1][1];
        double u1 = U[2][0] * U[0][1] - U[0][0] * U[2][1];
        double u2 = U[0][0] * U[1][1] - U[1][0] * U[0][1];
        double nr = sqrt(u0 * u0 + u1 * u1 + u2 * u2);
        if (nr > 1e-150) { U[0][2] = u0 / nr; U[1][2] = u1 / nr; U[2][2] = u2 / nr; }
    }
    double dU = det3(U), dV = det3(V);
    double s3 = (dU * dV >= 0.0) ? 1.0 : -1.0;
    double R[3][3];
    for (int i = 0; i < 3; i++)
        for (int j = 0; j < 3; j++)
            R[i][j] = U[i][0] * V[j][0] + U[i][1] * V[j][1] + s3 * U[i][2] * V[j][2];
    double mux[3] = {red[b * 16 + 9], red[b * 16 + 10], red[b * 16 + 11]};
    double muy[3] = {red[b * 16 + 12], red[b * 16 + 13], red[b * 16 + 14]};
    for (int i = 0; i < 3; i++) {
        for (int j = 0; j < 3; j++) outR[b * 9 + i * 3 + j] = (float)R[i][j];
        double t = muy[i] - (R[i][0] * mux[0] + R[i][1] * mux[1] + R[i][2] * mux[2]);
        outT[b * 3 + i] = (float)t;
    }
}

// ---------------------------------------------------------------------------
// host launcher
// ---------------------------------------------------------------------------
extern "C" void kernel_launch(void* const* d_in, const int* in_sizes, int n_in,
                              void* d_out, int out_size, void* d_ws, size_t ws_size,
                              hipStream_t stream) {
    const float* srcE = (const float*)d_in[0];
    const float* tgtE = (const float*)d_in[1];
    const float* srcP = (const float*)d_in[2];
    const float* tgtP = (const float*)d_in[3];
    float* out = (float*)d_out;  // R[36] T[12] corres[8192] weight[8192]

    char* w = (char*)d_ws;
    size_t off = 0;
    auto alloc = [&](size_t bytes) -> void* {
        void* p = w + off;
        off = (off + bytes + 255) & ~(size_t)255;
        return p;
    };
    float* corrTgt = (float*)alloc((size_t)NBATCH * NN * 3 * 4);
    int* corres = (int*)alloc((size_t)NBATCH * NN * 4);
    float* sq = (float*)alloc((size_t)NBATCH * NN * 4);
    float* pointLoss = (float*)alloc((size_t)NBATCH * NN * 4);
    float* minL = (float*)alloc(NBATCH * 4);
    float* weight = (float*)alloc((size_t)NBATCH * NN * 4);
    double* red = (double*)alloc(NBATCH * 16 * 8);
    size_t fixed = off;
    int nb = (ws_size >= fixed + (size_t)NBATCH * NN * NN * 4) ? NBATCH : 1;
    float* scores = (float*)alloc((size_t)nb * NN * NN * 4);

    compute_sq<<<(NBATCH * NN + 255) / 256, 256, 0, stream>>>(srcP, sq);

    for (int b0 = 0; b0 < NBATCH; b0 += nb) {
        gemm_scores_mfma<<<dim3(NN / 128, NN / 128, nb), 256, 0, stream>>>(srcE, tgtE, scores, b0);
        row_softmax<<<dim3(NN / 4, nb), 256, 0, stream>>>(scores, tgtP, corrTgt, corres, b0);
    }

    gfm_kernel<<<dim3(NN, NBATCH), 256, 0, stream>>>(srcP, corrTgt, sq, pointLoss);
    min_kernel<<<NBATCH, 256, 0, stream>>>(pointLoss, minL);
    weight_kernel<<<(NBATCH * NN + 255) / 256, 256, 0, stream>>>(
        pointLoss, minL, corres, weight, out + 48, out + 48 + NBATCH * NN);
    proc_reduce<<<NBATCH, 256, 0, stream>>>(srcP, tgtP, corres, weight, red);
    svd_finalize<<<1, 64, 0, stream>>>(red, out, out + 36);
}

// Round 4
// 230.772 us; speedup vs baseline: 2.3930x; 1.0998x over previous
//
#include <hip/hip_runtime.h>
#include <hip/hip_bf16.h>

#define NN 2048
#define DD 512
#define NBATCH 4
#define KNB 10
#define NPAIR 45

typedef __attribute__((ext_vector_type(8))) short bf16x8;
typedef __attribute__((ext_vector_type(4))) float f32x4;

// ---------------------------------------------------------------------------
// helpers
// ---------------------------------------------------------------------------
__device__ __forceinline__ float tri_area(float p0x, float p0y, float p0z,
                                          float p1x, float p1y, float p1z,
                                          float p2x, float p2y, float p2z) {
    float e1x = __fsub_rn(p1x, p0x), e1y = __fsub_rn(p1y, p0y), e1z = __fsub_rn(p1z, p0z);
    float e2x = __fsub_rn(p2x, p0x), e2y = __fsub_rn(p2y, p0y), e2z = __fsub_rn(p2z, p0z);
    float c0 = __fsub_rn(__fmul_rn(e1y, e2z), __fmul_rn(e1z, e2y));
    float c1 = __fsub_rn(__fmul_rn(e1z, e2x), __fmul_rn(e1x, e2z));
    float c2 = __fsub_rn(__fmul_rn(e1x, e2y), __fmul_rn(e1y, e2x));
    float ss = __fadd_rn(__fadd_rn(__fmul_rn(c0, c0), __fmul_rn(c1, c1)), __fmul_rn(c2, c2));
    return __fmul_rn(0.5f, sqrtf(ss));
}

__device__ __forceinline__ double wave_red_sum_d(double v) {
#pragma unroll
    for (int st = 1; st < 64; st <<= 1) v += __shfl_xor(v, st, 64);
    return v;
}

// ---------------------------------------------------------------------------
// K0: sq[b][n] = sum(x*x)
// ---------------------------------------------------------------------------
__global__ __launch_bounds__(256) void compute_sq(const float* __restrict__ srcP,
                                                  float* __restrict__ sq) {
    int i = blockIdx.x * 256 + threadIdx.x;
    if (i >= NBATCH * NN) return;
    int b = i / NN, n = i % NN;
    const float* xs = srcP + (size_t)b * 3 * NN;
    float x0 = xs[n], x1 = xs[NN + n], x2 = xs[2 * NN + n];
    sq[i] = __fadd_rn(__fadd_rn(__fmul_rn(x0, x0), __fmul_rn(x1, x1)), __fmul_rn(x2, x2));
}

// ---------------------------------------------------------------------------
// K1: MFMA bf16x6 split-precision GEMM.
// 128x128 tile, BK=32, 256 threads (4 waves, 2x2 of 64x64).
// LDS per plane: [row 0..127][k 0..31] bf16, 16B-granule XOR swizzle:
//   short_off(r,g) = r*32 + ((g ^ ((r>>1)&3))<<3), g = k>>3
// Writes are now ds_write_b128 (4 words/plane/8k) matching the read pattern:
// 2 lanes/bank -> conflict-free.
// ---------------------------------------------------------------------------
__global__ __launch_bounds__(256) void gemm_scores_mfma(const float* __restrict__ A,
                                                        const float* __restrict__ Bm,
                                                        float* __restrict__ S, int b0) {
    int b = b0 + blockIdx.z;
    const float* Ab = A + (size_t)b * DD * NN;
    const float* Bb = Bm + (size_t)b * DD * NN;
    float* Sb = S + (size_t)blockIdx.z * NN * NN;
    int n0 = blockIdx.y * 128, m0 = blockIdx.x * 128;

    __shared__ short As[3][128 * 32];
    __shared__ short Bs[3][128 * 32];

    int t = threadIdx.x;
    int w = t >> 6, lane = t & 63;
    int wr = w >> 1, wc = w & 1;
    int fr = lane & 15, kq = lane >> 4;

    int rr = t & 127;
    int rsw = (rr >> 1) & 3;
    const float* gp;
    short *PH, *PM, *PL;
    if (t < 128) {
        gp = Ab + n0 + rr;
        PH = &As[0][0]; PM = &As[1][0]; PL = &As[2][0];
    } else {
        gp = Bb + m0 + rr;
        PH = &Bs[0][0]; PM = &Bs[1][0]; PL = &Bs[2][0];
    }

    f32x4 acc[4][4];
#pragma unroll
    for (int i = 0; i < 4; i++)
#pragma unroll
        for (int j = 0; j < 4; j++) acc[i][j] = (f32x4){0.f, 0.f, 0.f, 0.f};

    for (int k0 = 0; k0 < DD; k0 += 32) {
        __syncthreads();  // protect previous iteration's fragment reads
#pragma unroll
        for (int g = 0; g < 4; g++) {
            unsigned h4[4], m4[4], l4[4];
#pragma unroll
            for (int p = 0; p < 4; p++) {
                int kk = g * 8 + p * 2;
                float x0 = gp[(size_t)(k0 + kk) * NN];
                float x1 = gp[(size_t)(k0 + kk + 1) * NN];
                unsigned hp, mp, lp;
                asm("v_cvt_pk_bf16_f32 %0, %1, %2" : "=v"(hp) : "v"(x0), "v"(x1));
                float h0 = __uint_as_float(hp << 16);
                float h1 = __uint_as_float(hp & 0xffff0000u);
                float r0 = __fsub_rn(x0, h0), r1 = __fsub_rn(x1, h1);
                asm("v_cvt_pk_bf16_f32 %0, %1, %2" : "=v"(mp) : "v"(r0), "v"(r1));
                float m0f = __uint_as_float(mp << 16);
                float m1f = __uint_as_float(mp & 0xffff0000u);
                float s0 = __fsub_rn(r0, m0f), s1 = __fsub_rn(r1, m1f);
                asm("v_cvt_pk_bf16_f32 %0, %1, %2" : "=v"(lp) : "v"(s0), "v"(s1));
                h4[p] = hp; m4[p] = mp; l4[p] = lp;
            }
            int soff = rr * 32 + ((g ^ rsw) << 3);  // shorts; 16B aligned
            *(uint4*)(PH + soff) = (uint4){h4[0], h4[1], h4[2], h4[3]};
            *(uint4*)(PM + soff) = (uint4){m4[0], m4[1], m4[2], m4[3]};
            *(uint4*)(PL + soff) = (uint4){l4[0], l4[1], l4[2], l4[3]};
        }
        __syncthreads();

        bf16x8 ah[4], am_[4], al[4], bh[4], bm_[4], bl[4];
#pragma unroll
        for (int i = 0; i < 4; i++) {
            int rA = wr * 64 + i * 16 + fr;
            int offA = rA * 32 + ((kq ^ ((rA >> 1) & 3)) << 3);
            ah[i] = *(const bf16x8*)&As[0][offA];
            am_[i] = *(const bf16x8*)&As[1][offA];
            al[i] = *(const bf16x8*)&As[2][offA];
            int rB = wc * 64 + i * 16 + fr;
            int offB = rB * 32 + ((kq ^ ((rB >> 1) & 3)) << 3);
            bh[i] = *(const bf16x8*)&Bs[0][offB];
            bm_[i] = *(const bf16x8*)&Bs[1][offB];
            bl[i] = *(const bf16x8*)&Bs[2][offB];
        }
#pragma unroll
        for (int i = 0; i < 4; i++)
#pragma unroll
            for (int j = 0; j < 4; j++) {
                f32x4 c = acc[i][j];
                c = __builtin_amdgcn_mfma_f32_16x16x32_bf16(ah[i], bh[j], c, 0, 0, 0);
                c = __builtin_amdgcn_mfma_f32_16x16x32_bf16(ah[i], bm_[j], c, 0, 0, 0);
                c = __builtin_amdgcn_mfma_f32_16x16x32_bf16(am_[i], bh[j], c, 0, 0, 0);
                c = __builtin_amdgcn_mfma_f32_16x16x32_bf16(am_[i], bm_[j], c, 0, 0, 0);
                c = __builtin_amdgcn_mfma_f32_16x16x32_bf16(ah[i], bl[j], c, 0, 0, 0);
                c = __builtin_amdgcn_mfma_f32_16x16x32_bf16(al[i], bh[j], c, 0, 0, 0);
                acc[i][j] = c;
            }
    }

#pragma unroll
    for (int i = 0; i < 4; i++) {
        int crow = n0 + wr * 64 + i * 16 + kq * 4;
#pragma unroll
        for (int j = 0; j < 4; j++) {
            int ccol = m0 + wc * 64 + j * 16 + fr;
#pragma unroll
            for (int rg = 0; rg < 4; rg++) {
                Sb[(size_t)(crow + rg) * NN + ccol] =
                    __fdiv_rn(acc[i][j][rg], 22.627416997969522f);
            }
        }
    }
}

// ---------------------------------------------------------------------------
// K2: wave-per-row argmax + softmax + corr_tgt; scores kept in 32 registers
// ---------------------------------------------------------------------------
__global__ __launch_bounds__(256) void row_softmax(const float* __restrict__ S,
                                                   const float* __restrict__ tgtP,
                                                   float* __restrict__ corrTgt,
                                                   int* __restrict__ corres, int b0) {
    int zb = blockIdx.y;
    int b = b0 + zb;
    int w = threadIdx.x >> 6, lane = threadIdx.x & 63;
    int n = blockIdx.x * 4 + w;
    const float* row = S + (size_t)zb * NN * NN + (size_t)n * NN;
    const float* tb = tgtP + (size_t)b * 3 * NN;

    float sv[32];
    float bm = -3.4e38f;
    int bi = 0x7fffffff;
#pragma unroll
    for (int c = 0; c < 8; c++) {
        int m = c * 256 + lane * 4;
        float4 v = *(const float4*)&row[m];
        float s0 = __fmul_rn(10000.0f, v.x);
        float s1 = __fmul_rn(10000.0f, v.y);
        float s2 = __fmul_rn(10000.0f, v.z);
        float s3 = __fmul_rn(10000.0f, v.w);
        sv[c * 4 + 0] = s0; sv[c * 4 + 1] = s1;
        sv[c * 4 + 2] = s2; sv[c * 4 + 3] = s3;
        if (s0 > bm) { bm = s0; bi = m; }
        if (s1 > bm) { bm = s1; bi = m + 1; }
        if (s2 > bm) { bm = s2; bi = m + 2; }
        if (s3 > bm) { bm = s3; bi = m + 3; }
    }
#pragma unroll
    for (int st = 1; st < 64; st <<= 1) {
        float ov = __shfl_xor(bm, st, 64);
        int oi = __shfl_xor(bi, st, 64);
        if (ov > bm || (ov == bm && oi < bi)) { bm = ov; bi = oi; }
    }
    float esum = 0.f, c0 = 0.f, c1 = 0.f, c2 = 0.f;
#pragma unroll
    for (int i = 0; i < 32; i++) {
        float d = __fsub_rn(sv[i], bm);
        if (d >= -90.0f) {  // exp(d) < 1e-39 contributes nothing in f32 — exact skip
            float e = expf(d);
            int mi = (i >> 2) * 256 + lane * 4 + (i & 3);
            esum = __fadd_rn(esum, e);
            c0 = fmaf(e, tb[mi], c0);
            c1 = fmaf(e, tb[NN + mi], c1);
            c2 = fmaf(e, tb[2 * NN + mi], c2);
        }
    }
#pragma unroll
    for (int st = 1; st < 64; st <<= 1) {
        esum += __shfl_xor(esum, st, 64);
        c0 += __shfl_xor(c0, st, 64);
        c1 += __shfl_xor(c1, st, 64);
        c2 += __shfl_xor(c2, st, 64);
    }
    if (lane == 0) {
        corres[b * NN + n] = bi;
        size_t o = ((size_t)b * NN + n) * 3;
        corrTgt[o + 0] = __fdiv_rn(c0, esum);
        corrTgt[o + 1] = __fdiv_rn(c1, esum);
        corrTgt[o + 2] = __fdiv_rn(c2, esum);
    }
}

// ---------------------------------------------------------------------------
// K3: GFM per anchor point
// ---------------------------------------------------------------------------
__global__ __launch_bounds__(256) void gfm_kernel(const float* __restrict__ srcP,
                                                  const float* __restrict__ corrTgt,
                                                  const float* __restrict__ sq,
                                                  float* __restrict__ pointLoss) {
    int b = blockIdx.y, n = blockIdx.x, tid = threadIdx.x;
    int w = tid >> 6, lane = tid & 63;
    const float* xs = srcP + (size_t)b * 3 * NN;
    __shared__ float wv4[4];
    __shared__ int wi4[4];
    __shared__ int nbIdx[KNB];
    __shared__ float ps[KNB][3], pt[KNB][3];
    __shared__ float lossA[NPAIR], regA[NPAIR], sorted1[NPAIR], loss2[NPAIR], sorted2[NPAIR];

    float a0 = xs[n], a1 = xs[NN + n], a2 = xs[2 * NN + n];
    float sqa = sq[b * NN + n];
    float v[8];
#pragma unroll
    for (int r = 0; r < 8; r++) {
        int m = tid + 256 * r;
        float x0 = xs[m], x1 = xs[NN + m], x2 = xs[2 * NN + m];
        float dot = __fadd_rn(__fadd_rn(__fmul_rn(a0, x0), __fmul_rn(a1, x1)), __fmul_rn(a2, x2));
        float d2 = __fsub_rn(__fadd_rn(sqa, sq[b * NN + m]), __fmul_rn(2.0f, dot));
        d2 = fmaxf(d2, 0.0f);
        float dd = sqrtf(d2);
        v[r] = expf(__fmul_rn(__fmul_rn(-dd, dd), 0.5f));
    }

    for (int it = 0; it < KNB; it++) {
        float lm = -10.f;
        int li = 0x7fffffff;
#pragma unroll
        for (int r = 0; r < 8; r++)
            if (v[r] > lm) { lm = v[r]; li = tid + 256 * r; }
#pragma unroll
        for (int st = 1; st < 64; st <<= 1) {
            float ov = __shfl_xor(lm, st, 64);
            int oi = __shfl_xor(li, st, 64);
            if (ov > lm || (ov == lm && oi < li)) { lm = ov; li = oi; }
        }
        if (lane == 0) { wv4[w] = lm; wi4[w] = li; }
        __syncthreads();
        float Vb = wv4[0];
        int Ib = wi4[0];
#pragma unroll
        for (int q = 1; q < 4; q++) {
            float ov = wv4[q];
            int oi = wi4[q];
            if (ov > Vb || (ov == Vb && oi < Ib)) { Vb = ov; Ib = oi; }
        }
        if (tid == (Ib & 255)) v[Ib >> 8] = -10.f;
        if (tid == 0) nbIdx[it] = Ib;
        __syncthreads();
    }

    if (tid < KNB) {
        int j = nbIdx[tid];
        ps[tid][0] = xs[j];
        ps[tid][1] = xs[NN + j];
        ps[tid][2] = xs[2 * NN + j];
        const float* ct = corrTgt + ((size_t)b * NN + j) * 3;
        pt[tid][0] = ct[0];
        pt[tid][1] = ct[1];
        pt[tid][2] = ct[2];
    }
    __syncthreads();

    if (tid < NPAIR) {
        int k = tid, ja = 0, cnt = 9;
        while (k >= cnt) { k -= cnt; ja++; cnt--; }
        int jb = ja + 1 + k;
        const float* ctn = corrTgt + ((size_t)b * NN + n) * 3;
        float area_s = tri_area(a0, a1, a2, ps[ja][0], ps[ja][1], ps[ja][2],
                                ps[jb][0], ps[jb][1], ps[jb][2]);
        float area_t = tri_area(ctn[0], ctn[1], ctn[2], pt[ja][0], pt[ja][1], pt[ja][2],
                                pt[jb][0], pt[jb][1], pt[jb][2]);
        const float EPSF = 1e-6f;
        float ee = __fmul_rn(EPSF, EPSF);
        float lt2 = __fadd_rn(area_t, EPSF);
        float da = __fsub_rn(area_s, lt2);
        float sa = __fadd_rn(area_s, lt2);
        float num = __fadd_rn(__fadd_rn(ee, ee), __fmul_rn(da, da));
        float den = __fadd_rn(__fadd_rn(ee, ee), __fmul_rn(sa, sa));
        lossA[tid] = __fdiv_rn(num, den);
        regA[tid] = sqrtf(num);
    }
    __syncthreads();

    if (tid < NPAIR) {  // rank sort #1 (stable)
        float x = lossA[tid];
        int rk = 0;
#pragma unroll 9
        for (int j = 0; j < NPAIR; j++) {
            float y = lossA[j];
            rk += (y < x || (y == x && j < tid)) ? 1 : 0;
        }
        sorted1[rk] = x;
    }
    __syncthreads();
    if (tid < NPAIR) loss2[tid] = __fadd_rn(sorted1[tid], __fmul_rn(0.1f, regA[tid]));
    __syncthreads();
    if (tid < NPAIR) {  // rank sort #2
        float x = loss2[tid];
        int rk = 0;
#pragma unroll 9
        for (int j = 0; j < NPAIR; j++) {
            float y = loss2[j];
            rk += (y < x || (y == x && j < tid)) ? 1 : 0;
        }
        sorted2[rk] = x;
    }
    __syncthreads();
    if (tid == 0) {
        float med = sorted2[22];
        float thr = __fmul_rn(3.0f, med);
        float sum = 0.f;
        for (int k2 = 0; k2 < KNB; k2++) {
            float vv = loss2[k2];
            if (vv > thr) vv = 0.f;
            sum = __fadd_rn(sum, sqrtf(__fadd_rn(vv, 1e-6f)));
        }
        pointLoss[b * NN + n] = __fdiv_rn(sum, 10.0f);
    }
}

// ---------------------------------------------------------------------------
// K4: per-batch min of pointLoss
// ---------------------------------------------------------------------------
__global__ __launch_bounds__(256) void min_kernel(const float* __restrict__ pl,
                                                  float* __restrict__ minL) {
    int b = blockIdx.x, tid = threadIdx.x;
    __shared__ float sd[256];
    float m = 3.4e38f;
    for (int n = tid; n < NN; n += 256) m = fminf(m, pl[b * NN + n]);
    sd[tid] = m;
    __syncthreads();
    for (int st = 128; st > 0; st >>= 1) {
        if (tid < st) sd[tid] = fminf(sd[tid], sd[tid + st]);
        __syncthreads();
    }
    if (tid == 0) minL[b] = sd[0];
}

// ---------------------------------------------------------------------------
// K5: weight + f32 outputs for corres & weight
// ---------------------------------------------------------------------------
__global__ __launch_bounds__(256) void weight_kernel(const float* __restrict__ pl,
                                                     const float* __restrict__ minL,
                                                     const int* __restrict__ corres,
                                                     float* __restrict__ weight,
                                                     float* __restrict__ outC,
                                                     float* __restrict__ outW) {
    int i = blockIdx.x * 256 + threadIdx.x;
    if (i >= NBATCH * NN) return;
    int b = i / NN;
    float l = __fsub_rn(pl[i], minL[b]);
    float z = __fmul_rn(-20.0f, l);
    float ez = expf(z);
    float sg = __fdiv_rn(ez, __fadd_rn(1.0f, ez));
    float w2 = __fmul_rn(2.0f, sg);
    float wf = (w2 > 0.5f) ? 1.0f : 0.0f;
    weight[i] = wf;
    outW[i] = wf;
    outC[i] = (float)corres[i];
}

// ---------------------------------------------------------------------------
// K6: per-batch Procrustes reductions (double, shuffle-based)
// red[b*16 + 0..8]=Sxy, +9..11=mux, +12..14=muy, +15=W1
// ---------------------------------------------------------------------------
__global__ __launch_bounds__(256) void proc_reduce(const float* __restrict__ srcP,
                                                   const float* __restrict__ tgtP,
                                                   const int* __restrict__ corres,
                                                   const float* __restrict__ weight,
                                                   double* __restrict__ red) {
    int b = blockIdx.x, tid = threadIdx.x;
    int w = tid >> 6, lane = tid & 63;
    __shared__ double sd[4][9];
    const float* xs = srcP + (size_t)b * 3 * NN;
    const float* ts = tgtP + (size_t)b * 3 * NN;
    const int* cr = corres + b * NN;
    const float* wv = weight + b * NN;

    double acc7[7] = {0, 0, 0, 0, 0, 0, 0};  // cw, cx0..2, cy0..2
    for (int nn2 = tid; nn2 < NN; nn2 += 256) {
        if (wv[nn2] != 0.0f) {
            acc7[0] += 1.0;
            acc7[1] += (double)xs[nn2];
            acc7[2] += (double)xs[NN + nn2];
            acc7[3] += (double)xs[2 * NN + nn2];
            int m = cr[nn2];
            acc7[4] += (double)ts[m];
            acc7[5] += (double)ts[NN + m];
            acc7[6] += (double)ts[2 * NN + m];
        }
    }
#pragma unroll
    for (int q = 0; q < 7; q++) {
        double r = wave_red_sum_d(acc7[q]);
        if (lane == 0) sd[w][q] = r;
    }
    __syncthreads();
    double tot7[7];
#pragma unroll
    for (int q = 0; q < 7; q++)
        tot7[q] = sd[0][q] + sd[1][q] + sd[2][q] + sd[3][q];
    __syncthreads();

    double W1e = tot7[0] + 1e-7;
    double mux0 = tot7[1] / W1e, mux1 = tot7[2] / W1e, mux2 = tot7[3] / W1e;
    double muy0 = tot7[4] / W1e, muy1 = tot7[5] / W1e, muy2 = tot7[6] / W1e;

    double s[9] = {0, 0, 0, 0, 0, 0, 0, 0, 0};
    for (int nn2 = tid; nn2 < NN; nn2 += 256) {
        if (wv[nn2] != 0.0f) {
            double dx0 = (double)xs[nn2] - mux0;
            double dx1 = (double)xs[NN + nn2] - mux1;
            double dx2 = (double)xs[2 * NN + nn2] - mux2;
            int m = cr[nn2];
            double dy0 = (double)ts[m] - muy0;
            double dy1 = (double)ts[NN + m] - muy1;
            double dy2 = (double)ts[2 * NN + m] - muy2;
            s[0] += dy0 * dx0; s[1] += dy0 * dx1; s[2] += dy0 * dx2;
            s[3] += dy1 * dx0; s[4] += dy1 * dx1; s[5] += dy1 * dx2;
            s[6] += dy2 * dx0; s[7] += dy2 * dx1; s[8] += dy2 * dx2;
        }
    }
#pragma unroll
    for (int q = 0; q < 9; q++) {
        double r = wave_red_sum_d(s[q]);
        if (lane == 0) sd[w][q] = r;
    }
    __syncthreads();
    if (tid < 9) {
        double tot = sd[0][tid] + sd[1][tid] + sd[2][tid] + sd[3][tid];
        red[b * 16 + tid] = tot / W1e;
    }
    if (tid == 9) {
        red[b * 16 + 9] = mux0; red[b * 16 + 10] = mux1; red[b * 16 + 11] = mux2;
        red[b * 16 + 12] = muy0; red[b * 16 + 13] = muy1; red[b * 16 + 14] = muy2;
        red[b * 16 + 15] = W1e;
    }
}

// ---------------------------------------------------------------------------
// K7: 3x3 SVD (one-sided Jacobi, f64) -> R, T
// ---------------------------------------------------------------------------
__device__ double det3(const double M[3][3]) {
    return M[0][0] * (M[1][1] * M[2][2] - M[1][2] * M[2][1]) -
           M[0][1] * (M[1][0] * M[2][2] - M[1][2] * M[2][0]) +
           M[0][2] * (M[1][0] * M[2][1] - M[1][1] * M[2][0]);
}

__global__ void svd_finalize(const double* __restrict__ red,
                             float* __restrict__ outR,
                             float* __restrict__ outT) {
    int b = threadIdx.x;
    if (b >= NBATCH) return;
    double A[3][3], Bm[3][3], V[3][3];
    for (int r = 0; r < 3; r++)
        for (int c2 = 0; c2 < 3; c2++) {
            A[r][c2] = red[b * 16 + r * 3 + c2];
            Bm[r][c2] = A[r][c2];
            V[r][c2] = (r == c2) ? 1.0 : 0.0;
        }
    double nrm2 = 0;
    for (int r = 0; r < 3; r++)
        for (int c2 = 0; c2 < 3; c2++) nrm2 += Bm[r][c2] * Bm[r][c2];

    for (int sweep = 0; sweep < 60; sweep++) {
        double off = 0;
        for (int p = 0; p < 2; p++) {
            for (int q = p + 1; q < 3; q++) {
                double al = 0, be = 0, ga = 0;
                for (int i = 0; i < 3; i++) {
                    al += Bm[i][p] * Bm[i][p];
                    be += Bm[i][q] * Bm[i][q];
                    ga += Bm[i][p] * Bm[i][q];
                }
                off += ga * ga;
                if (fabs(ga) > 1e-300) {
                    double ze = (be - al) / (2.0 * ga);
                    double t = copysign(1.0, ze) / (fabs(ze) + sqrt(1.0 + ze * ze));
                    double c = 1.0 / sqrt(1.0 + t * t), sn = c * t;
                    for (int i = 0; i < 3; i++) {
                        double bp = Bm[i][p], bq = Bm[i][q];
                        Bm[i][p] = c * bp - sn * bq;
                        Bm[i][q] = sn * bp + c * bq;
                        double vp = V[i][p], vq = V[i][q];
                        V[i][p] = c * vp - sn * vq;
                        V[i][q] = sn * vp + c * vq;
                    }
                }
            }
        }
        if (off <= 1e-30 * nrm2 * nrm2) break;
    }
    double sig[3];
    for (int j = 0; j < 3; j++) {
        double ss = 0;
        for (int i = 0; i < 3; i++) ss += Bm[i][j] * Bm[i][j];
        sig[j] = sqrt(ss);
    }
    for (int a = 0; a < 2; a++)
        for (int j = 0; j < 2 - a; j++)
            if (sig[j] < sig[j + 1]) {
                double t = sig[j]; sig[j] = sig[j + 1]; sig[j + 1] = t;
                for (int i = 0; i < 3; i++) {
                    double tb = Bm[i][j]; Bm[i][j] = Bm[i][j + 1]; Bm[i][j + 1] = tb;
                    double tv = V[i][j]; V[i][j] = V[i][j + 1]; V[i][j + 1] = tv;
                }
            }
    double U[3][3];
    for (int j = 0; j < 3; j++) {
        double inv = (sig[j] > 1e-150) ? 1.0 / sig[j] : 0.0;
        for (int i = 0; i < 3; i++) U[i][j] = Bm[i][j] * inv;
    }
    if (sig[2] <= 1e-10 * (sig[0] + 1e-300)) {
        double u0 = U[1][0] * U[2][1] - U[2][0] * U[1][1];
        double u1 = U[2][0] * U[0][1] - U[0][0] * U[2][1];
        double u2 = U[0][0] * U[1][1] - U[1][0] * U[0][1];
        double nr = sqrt(u0 * u0 + u1 * u1 + u2 * u2);
        if (nr > 1e-150) { U[0][2] = u0 / nr; U[1][2] = u1 / nr; U[2][2] = u2 / nr; }
    }
    double dU = det3(U), dV = det3(V);
    double s3 = (dU * dV >= 0.0) ? 1.0 : -1.0;
    double R[3][3];
    for (int i = 0; i < 3; i++)
        for (int j = 0; j < 3; j++)
            R[i][j] = U[i][0] * V[j][0] + U[i][1] * V[j][1] + s3 * U[i][2] * V[j][2];
    double mux[3] = {red[b * 16 + 9], red[b * 16 + 10], red[b * 16 + 11]};
    double muy[3] = {red[b * 16 + 12], red[b * 16 + 13], red[b * 16 + 14]};
    for (int i = 0; i < 3; i++) {
        for (int j = 0; j < 3; j++) outR[b * 9 + i * 3 + j] = (float)R[i][j];
        double t = muy[i] - (R[i][0] * mux[0] + R[i][1] * mux[1] + R[i][2] * mux[2]);
        outT[b * 3 + i] = (float)t;
    }
}

// ---------------------------------------------------------------------------
// host launcher
// ---------------------------------------------------------------------------
extern "C" void kernel_launch(void* const* d_in, const int* in_sizes, int n_in,
                              void* d_out, int out_size, void* d_ws, size_t ws_size,
                              hipStream_t stream) {
    const float* srcE = (const float*)d_in[0];
    const float* tgtE = (const float*)d_in[1];
    const float* srcP = (const float*)d_in[2];
    const float* tgtP = (const float*)d_in[3];
    float* out = (float*)d_out;  // R[36] T[12] corres[8192] weight[8192]

    char* w = (char*)d_ws;
    size_t off = 0;
    auto alloc = [&](size_t bytes) -> void* {
        void* p = w + off;
        off = (off + bytes + 255) & ~(size_t)255;
        return p;
    };
    float* corrTgt = (float*)alloc((size_t)NBATCH * NN * 3 * 4);
    int* corres = (int*)alloc((size_t)NBATCH * NN * 4);
    float* sq = (float*)alloc((size_t)NBATCH * NN * 4);
    float* pointLoss = (float*)alloc((size_t)NBATCH * NN * 4);
    float* minL = (float*)alloc(NBATCH * 4);
    float* weight = (float*)alloc((size_t)NBATCH * NN * 4);
    double* red = (double*)alloc(NBATCH * 16 * 8);
    size_t fixed = off;
    int nb = (ws_size >= fixed + (size_t)NBATCH * NN * NN * 4) ? NBATCH : 1;
    float* scores = (float*)alloc((size_t)nb * NN * NN * 4);

    compute_sq<<<(NBATCH * NN + 255) / 256, 256, 0, stream>>>(srcP, sq);

    for (int b0 = 0; b0 < NBATCH; b0 += nb) {
        gemm_scores_mfma<<<dim3(NN / 128, NN / 128, nb), 256, 0, stream>>>(srcE, tgtE, scores, b0);
        row_softmax<<<dim3(NN / 4, nb), 256, 0, stream>>>(scores, tgtP, corrTgt, corres, b0);
    }

    gfm_kernel<<<dim3(NN, NBATCH), 256, 0, stream>>>(srcP, corrTgt, sq, pointLoss);
    min_kernel<<<NBATCH, 256, 0, stream>>>(pointLoss, minL);
    weight_kernel<<<(NBATCH * NN + 255) / 256, 256, 0, stream>>>(
        pointLoss, minL, corres, weight, out + 48, out + 48 + NBATCH * NN);
    proc_reduce<<<NBATCH, 256, 0, stream>>>(srcP, tgtP, corres, weight, red);
    svd_finalize<<<1, 64, 0, stream>>>(red, out, out + 36);
}

// Round 5
// 210.742 us; speedup vs baseline: 2.6205x; 1.0950x over previous
//
#include <hip/hip_runtime.h>
#include <hip/hip_bf16.h>

#define NN 2048
#define DD 512
#define NBATCH 4
#define KNB 10
#define NPAIR 45

typedef __attribute__((ext_vector_type(8))) short bf16x8;
typedef __attribute__((ext_vector_type(4))) float f32x4;

// ---------------------------------------------------------------------------
// helpers
// ---------------------------------------------------------------------------
__device__ __forceinline__ float tri_area(float p0x, float p0y, float p0z,
                                          float p1x, float p1y, float p1z,
                                          float p2x, float p2y, float p2z) {
    float e1x = __fsub_rn(p1x, p0x), e1y = __fsub_rn(p1y, p0y), e1z = __fsub_rn(p1z, p0z);
    float e2x = __fsub_rn(p2x, p0x), e2y = __fsub_rn(p2y, p0y), e2z = __fsub_rn(p2z, p0z);
    float c0 = __fsub_rn(__fmul_rn(e1y, e2z), __fmul_rn(e1z, e2y));
    float c1 = __fsub_rn(__fmul_rn(e1z, e2x), __fmul_rn(e1x, e2z));
    float c2 = __fsub_rn(__fmul_rn(e1x, e2y), __fmul_rn(e1y, e2x));
    float ss = __fadd_rn(__fadd_rn(__fmul_rn(c0, c0), __fmul_rn(c1, c1)), __fmul_rn(c2, c2));
    return __fmul_rn(0.5f, sqrtf(ss));
}

__device__ __forceinline__ double wave_red_sum_d(double v) {
#pragma unroll
    for (int st = 1; st < 64; st <<= 1) v += __shfl_xor(v, st, 64);
    return v;
}

// ---------------------------------------------------------------------------
// K1: MFMA bf16 2-plane 3-product GEMM (cheap path; flagged rows refined).
// 128x128 tile, BK=32, 256 threads (4 waves, 2x2 of 64x64).
// LDS per plane: [row][k] bf16, 16B-granule XOR swizzle (conflict-free R+W).
// ---------------------------------------------------------------------------
__global__ __launch_bounds__(256) void gemm_scores_mfma(const float* __restrict__ A,
                                                        const float* __restrict__ Bm,
                                                        float* __restrict__ S, int b0) {
    int b = b0 + blockIdx.z;
    const float* Ab = A + (size_t)b * DD * NN;
    const float* Bb = Bm + (size_t)b * DD * NN;
    float* Sb = S + (size_t)blockIdx.z * NN * NN;
    int n0 = blockIdx.y * 128, m0 = blockIdx.x * 128;

    __shared__ short As[2][128 * 32];
    __shared__ short Bs[2][128 * 32];

    int t = threadIdx.x;
    int w = t >> 6, lane = t & 63;
    int wr = w >> 1, wc = w & 1;
    int fr = lane & 15, kq = lane >> 4;

    int rr = t & 127;
    int rsw = (rr >> 1) & 3;
    const float* gp;
    short *PH, *PM;
    if (t < 128) {
        gp = Ab + n0 + rr;
        PH = &As[0][0]; PM = &As[1][0];
    } else {
        gp = Bb + m0 + rr;
        PH = &Bs[0][0]; PM = &Bs[1][0];
    }

    f32x4 acc[4][4];
#pragma unroll
    for (int i = 0; i < 4; i++)
#pragma unroll
        for (int j = 0; j < 4; j++) acc[i][j] = (f32x4){0.f, 0.f, 0.f, 0.f};

    for (int k0 = 0; k0 < DD; k0 += 32) {
        __syncthreads();
#pragma unroll
        for (int g = 0; g < 4; g++) {
            unsigned h4[4], m4[4];
#pragma unroll
            for (int p = 0; p < 4; p++) {
                int kk = g * 8 + p * 2;
                float x0 = gp[(size_t)(k0 + kk) * NN];
                float x1 = gp[(size_t)(k0 + kk + 1) * NN];
                unsigned hp, mp;
                asm("v_cvt_pk_bf16_f32 %0, %1, %2" : "=v"(hp) : "v"(x0), "v"(x1));
                float h0 = __uint_as_float(hp << 16);
                float h1 = __uint_as_float(hp & 0xffff0000u);
                float r0 = __fsub_rn(x0, h0), r1 = __fsub_rn(x1, h1);
                asm("v_cvt_pk_bf16_f32 %0, %1, %2" : "=v"(mp) : "v"(r0), "v"(r1));
                h4[p] = hp; m4[p] = mp;
            }
            int soff = rr * 32 + ((g ^ rsw) << 3);  // shorts; 16B aligned
            *(uint4*)(PH + soff) = (uint4){h4[0], h4[1], h4[2], h4[3]};
            *(uint4*)(PM + soff) = (uint4){m4[0], m4[1], m4[2], m4[3]};
        }
        __syncthreads();

        bf16x8 ah[4], am_[4], bh[4], bm_[4];
#pragma unroll
        for (int i = 0; i < 4; i++) {
            int rA = wr * 64 + i * 16 + fr;
            int offA = rA * 32 + ((kq ^ ((rA >> 1) & 3)) << 3);
            ah[i] = *(const bf16x8*)&As[0][offA];
            am_[i] = *(const bf16x8*)&As[1][offA];
            int rB = wc * 64 + i * 16 + fr;
            int offB = rB * 32 + ((kq ^ ((rB >> 1) & 3)) << 3);
            bh[i] = *(const bf16x8*)&Bs[0][offB];
            bm_[i] = *(const bf16x8*)&Bs[1][offB];
        }
#pragma unroll
        for (int i = 0; i < 4; i++)
#pragma unroll
            for (int j = 0; j < 4; j++) {
                f32x4 c = acc[i][j];
                c = __builtin_amdgcn_mfma_f32_16x16x32_bf16(ah[i], bh[j], c, 0, 0, 0);
                c = __builtin_amdgcn_mfma_f32_16x16x32_bf16(ah[i], bm_[j], c, 0, 0, 0);
                c = __builtin_amdgcn_mfma_f32_16x16x32_bf16(am_[i], bh[j], c, 0, 0, 0);
                acc[i][j] = c;
            }
    }

#pragma unroll
    for (int i = 0; i < 4; i++) {
        int crow = n0 + wr * 64 + i * 16 + kq * 4;
#pragma unroll
        for (int j = 0; j < 4; j++) {
            int ccol = m0 + wc * 64 + j * 16 + fr;
#pragma unroll
            for (int rg = 0; rg < 4; rg++) {
                Sb[(size_t)(crow + rg) * NN + ccol] =
                    __fdiv_rn(acc[i][j][rg], 22.627416997969522f);
            }
        }
    }
}

// ---------------------------------------------------------------------------
// K2: wave-per-row argmax + top2-gap flag + softmax + corr_tgt
// ---------------------------------------------------------------------------
__global__ __launch_bounds__(256) void row_softmax(const float* __restrict__ S,
                                                   const float* __restrict__ tgtP,
                                                   float* __restrict__ corrTgt,
                                                   int* __restrict__ corres,
                                                   int* __restrict__ flags, int b0) {
    int zb = blockIdx.y;
    int b = b0 + zb;
    int w = threadIdx.x >> 6, lane = threadIdx.x & 63;
    int n = blockIdx.x * 4 + w;
    const float* row = S + (size_t)zb * NN * NN + (size_t)n * NN;
    const float* tb = tgtP + (size_t)b * 3 * NN;

    float sv[32];
    float bm = -3.4e38f, sm = -3.4e38f;
    int bi = 0x7fffffff;
#pragma unroll
    for (int c = 0; c < 8; c++) {
        int m = c * 256 + lane * 4;
        float4 v = *(const float4*)&row[m];
        float s0 = __fmul_rn(10000.0f, v.x);
        float s1 = __fmul_rn(10000.0f, v.y);
        float s2 = __fmul_rn(10000.0f, v.z);
        float s3 = __fmul_rn(10000.0f, v.w);
        sv[c * 4 + 0] = s0; sv[c * 4 + 1] = s1;
        sv[c * 4 + 2] = s2; sv[c * 4 + 3] = s3;
        if (s0 > bm) { sm = bm; bm = s0; bi = m; } else if (s0 > sm) sm = s0;
        if (s1 > bm) { sm = bm; bm = s1; bi = m + 1; } else if (s1 > sm) sm = s1;
        if (s2 > bm) { sm = bm; bm = s2; bi = m + 2; } else if (s2 > sm) sm = s2;
        if (s3 > bm) { sm = bm; bm = s3; bi = m + 3; } else if (s3 > sm) sm = s3;
    }
#pragma unroll
    for (int st = 1; st < 64; st <<= 1) {
        float obm = __shfl_xor(bm, st, 64);
        float osm = __shfl_xor(sm, st, 64);
        int oi = __shfl_xor(bi, st, 64);
        if (obm > bm || (obm == bm && oi < bi)) {
            sm = fmaxf(bm, osm); bm = obm; bi = oi;
        } else {
            sm = fmaxf(obm, sm);
        }
    }
    float esum = 0.f, c0 = 0.f, c1 = 0.f, c2 = 0.f;
#pragma unroll
    for (int i = 0; i < 32; i++) {
        float d = __fsub_rn(sv[i], bm);
        if (d >= -90.0f) {  // exp underflows vs max term 1.0 — exact skip
            float e = expf(d);
            int mi = (i >> 2) * 256 + lane * 4 + (i & 3);
            esum = __fadd_rn(esum, e);
            c0 = fmaf(e, tb[mi], c0);
            c1 = fmaf(e, tb[NN + mi], c1);
            c2 = fmaf(e, tb[2 * NN + mi], c2);
        }
    }
#pragma unroll
    for (int st = 1; st < 64; st <<= 1) {
        esum += __shfl_xor(esum, st, 64);
        c0 += __shfl_xor(c0, st, 64);
        c1 += __shfl_xor(c1, st, 64);
        c2 += __shfl_xor(c2, st, 64);
    }
    if (lane == 0) {
        corres[b * NN + n] = bi;
        flags[b * NN + n] = (__fsub_rn(bm, sm) < 24.0f) ? 1 : 0;  // ~70x error margin
        size_t o = ((size_t)b * NN + n) * 3;
        corrTgt[o + 0] = __fdiv_rn(c0, esum);
        corrTgt[o + 1] = __fdiv_rn(c1, esum);
        corrTgt[o + 2] = __fdiv_rn(c2, esum);
    }
}

// ---------------------------------------------------------------------------
// K2b: exact f32 argmax recompute for flagged rows. 8 blocks/row, atomicMax
// on key = (ordered_u32(score) << 32) | ~m  (first-index tie-break).
// ---------------------------------------------------------------------------
__global__ __launch_bounds__(256) void refine_argmax(const float* __restrict__ A,
                                                     const float* __restrict__ Bm,
                                                     const int* __restrict__ flags,
                                                     unsigned long long* __restrict__ keys) {
    int row = blockIdx.y;
    if (!flags[row]) return;
    int b = row / NN, n = row % NN;
    int tid = threadIdx.x;
    __shared__ float Acol[DD];
    const float* Ab = A + (size_t)b * DD * NN;
    const float* Bb = Bm + (size_t)b * DD * NN;
    Acol[tid] = Ab[(size_t)tid * NN + n];
    Acol[tid + 256] = Ab[(size_t)(tid + 256) * NN + n];
    __syncthreads();
    int m = blockIdx.x * 256 + tid;
    float acc = 0.f;
    for (int d = 0; d < DD; d++) acc = fmaf(Acol[d], Bb[(size_t)d * NN + m], acc);
    // replicate ref transform chain for tie structure
    float sc = __fmul_rn(10000.0f, __fdiv_rn(acc, 22.627416997969522f));
    unsigned u = __float_as_uint(sc);
    u = (u & 0x80000000u) ? ~u : (u | 0x80000000u);  // order-preserving map
    unsigned long long key = ((unsigned long long)u << 32) | (unsigned)(~(unsigned)m);
    atomicMax(&keys[row], key);
}

// ---------------------------------------------------------------------------
// K3: GFM wave-per-point: staged cloud in LDS, register top-10, per-wave sorts
// ---------------------------------------------------------------------------
__global__ __launch_bounds__(256) void gfm_kernel(const float* __restrict__ srcP,
                                                  const float* __restrict__ corrTgt,
                                                  float* __restrict__ pointLoss) {
    int b = blockIdx.y, tid = threadIdx.x;
    int w = tid >> 6, lane = tid & 63;
    int n = blockIdx.x * 4 + w;
    __shared__ float X0[NN], X1[NN], X2[NN], SQ[NN];
    __shared__ int nbl[4][KNB];
    __shared__ float ptb[4][KNB][3];
    __shared__ float la[4][NPAIR], rg[4][NPAIR], srt[4][NPAIR];
    const float* xs = srcP + (size_t)b * 3 * NN;

    for (int i = tid; i < NN / 4; i += 256) {
        float4 u0 = ((const float4*)xs)[i];
        float4 u1 = ((const float4*)(xs + NN))[i];
        float4 u2 = ((const float4*)(xs + 2 * NN))[i];
        ((float4*)X0)[i] = u0;
        ((float4*)X1)[i] = u1;
        ((float4*)X2)[i] = u2;
        float4 q;
        q.x = __fadd_rn(__fadd_rn(__fmul_rn(u0.x, u0.x), __fmul_rn(u1.x, u1.x)), __fmul_rn(u2.x, u2.x));
        q.y = __fadd_rn(__fadd_rn(__fmul_rn(u0.y, u0.y), __fmul_rn(u1.y, u1.y)), __fmul_rn(u2.y, u2.y));
        q.z = __fadd_rn(__fadd_rn(__fmul_rn(u0.z, u0.z), __fmul_rn(u1.z, u1.z)), __fmul_rn(u2.z, u2.z));
        q.w = __fadd_rn(__fadd_rn(__fmul_rn(u0.w, u0.w), __fmul_rn(u1.w, u1.w)), __fmul_rn(u2.w, u2.w));
        ((float4*)SQ)[i] = q;
    }
    __syncthreads();

    float a0 = X0[n], a1 = X1[n], a2 = X2[n], sqa = SQ[n];
    // key = -d2: weakly monotone with w=exp(-d^2/2); compression ties only
    // perturb neighbor choice -> weight +-1 (under threshold)
    float v[32];
#pragma unroll
    for (int r = 0; r < 32; r++) {
        int m = lane + 64 * r;
        float dot = __fadd_rn(__fadd_rn(__fmul_rn(a0, X0[m]), __fmul_rn(a1, X1[m])),
                              __fmul_rn(a2, X2[m]));
        float d2 = __fsub_rn(__fadd_rn(sqa, SQ[m]), __fmul_rn(2.0f, dot));
        v[r] = -fmaxf(d2, 0.0f);
    }
    unsigned removed = 0;
#pragma unroll
    for (int it = 0; it < KNB; it++) {
        float lm = -3.5e38f;
        int li = 0x7fffffff;
#pragma unroll
        for (int r = 0; r < 32; r++) {
            float vv = ((removed >> r) & 1u) ? -3.5e38f : v[r];
            int m = lane + 64 * r;
            if (vv > lm) { lm = vv; li = m; }
        }
#pragma unroll
        for (int st = 1; st < 64; st <<= 1) {
            float ov = __shfl_xor(lm, st, 64);
            int oi = __shfl_xor(li, st, 64);
            if (ov > lm || (ov == lm && oi < li)) { lm = ov; li = oi; }
        }
        if (lane == 0) nbl[w][it] = li;
        removed |= ((li & 63) == lane) ? (1u << (li >> 6)) : 0u;
    }
    __builtin_amdgcn_wave_barrier();
    if (lane < KNB) {
        int ia = nbl[w][lane];
        const float* ct = corrTgt + ((size_t)b * NN + ia) * 3;
        ptb[w][lane][0] = ct[0];
        ptb[w][lane][1] = ct[1];
        ptb[w][lane][2] = ct[2];
    }
    __builtin_amdgcn_wave_barrier();
    const float* ctn = corrTgt + ((size_t)b * NN + n) * 3;
    float t0 = ctn[0], t1 = ctn[1], t2 = ctn[2];
    if (lane < NPAIR) {
        int k = lane, ja = 0, cnt = 9;
        while (k >= cnt) { k -= cnt; ja++; cnt--; }
        int jb = ja + 1 + k;
        int ia = nbl[w][ja], ib = nbl[w][jb];
        float area_s = tri_area(a0, a1, a2, X0[ia], X1[ia], X2[ia], X0[ib], X1[ib], X2[ib]);
        float area_t = tri_area(t0, t1, t2, ptb[w][ja][0], ptb[w][ja][1], ptb[w][ja][2],
                                ptb[w][jb][0], ptb[w][jb][1], ptb[w][jb][2]);
        const float EPSF = 1e-6f;
        float ee = __fmul_rn(EPSF, EPSF);
        float lt2 = __fadd_rn(area_t, EPSF);
        float da = __fsub_rn(area_s, lt2);
        float sa = __fadd_rn(area_s, lt2);
        float num = __fadd_rn(__fadd_rn(ee, ee), __fmul_rn(da, da));
        float den = __fadd_rn(__fadd_rn(ee, ee), __fmul_rn(sa, sa));
        la[w][lane] = __fdiv_rn(num, den);
        rg[w][lane] = sqrtf(num);
    }
    __builtin_amdgcn_wave_barrier();
    if (lane < NPAIR) {  // stable rank sort #1
        float x = la[w][lane];
        int rk = 0;
        for (int j = 0; j < NPAIR; j++) {
            float y = la[w][j];
            rk += (y < x || (y == x && j < lane)) ? 1 : 0;
        }
        srt[w][rk] = x;
    }
    __builtin_amdgcn_wave_barrier();
    float l2v = 0.f;
    if (lane < NPAIR) l2v = __fadd_rn(srt[w][lane], __fmul_rn(0.1f, rg[w][lane]));
    __builtin_amdgcn_wave_barrier();
    if (lane < NPAIR) la[w][lane] = l2v;
    __builtin_amdgcn_wave_barrier();
    if (lane < NPAIR) {  // stable rank sort #2
        float x = la[w][lane];
        int rk = 0;
        for (int j = 0; j < NPAIR; j++) {
            float y = la[w][j];
            rk += (y < x || (y == x && j < lane)) ? 1 : 0;
        }
        srt[w][rk] = x;
    }
    __builtin_amdgcn_wave_barrier();
    float med = srt[w][22];
    float thr = __fmul_rn(3.0f, med);
    float term = 0.f;
    if (lane < KNB) {
        float vv = la[w][lane];
        if (vv > thr) vv = 0.f;
        term = sqrtf(__fadd_rn(vv, 1e-6f));
    }
#pragma unroll
    for (int st = 1; st < 64; st <<= 1) term += __shfl_xor(term, st, 64);
    if (lane == 0) pointLoss[b * NN + n] = __fdiv_rn(term, 10.0f);
}

// ---------------------------------------------------------------------------
// K4: per-batch min of pointLoss
// ---------------------------------------------------------------------------
__global__ __launch_bounds__(256) void min_kernel(const float* __restrict__ pl,
                                                  float* __restrict__ minL) {
    int b = blockIdx.x, tid = threadIdx.x;
    __shared__ float sd[256];
    float m = 3.4e38f;
    for (int n = tid; n < NN; n += 256) m = fminf(m, pl[b * NN + n]);
    sd[tid] = m;
    __syncthreads();
    for (int st = 128; st > 0; st >>= 1) {
        if (tid < st) sd[tid] = fminf(sd[tid], sd[tid + st]);
        __syncthreads();
    }
    if (tid == 0) minL[b] = sd[0];
}

// ---------------------------------------------------------------------------
// K5: weight + refined-corres unpack + f32 outputs
// ---------------------------------------------------------------------------
__global__ __launch_bounds__(256) void weight_kernel(const float* __restrict__ pl,
                                                     const float* __restrict__ minL,
                                                     int* __restrict__ corres,
                                                     const int* __restrict__ flags,
                                                     const unsigned long long* __restrict__ keys,
                                                     float* __restrict__ weight,
                                                     float* __restrict__ outC,
                                                     float* __restrict__ outW) {
    int i = blockIdx.x * 256 + threadIdx.x;
    if (i >= NBATCH * NN) return;
    int b = i / NN;
    int ci = corres[i];
    if (flags[i]) {
        ci = (int)(~(unsigned)(keys[i] & 0xFFFFFFFFull));
        corres[i] = ci;  // for proc_reduce
    }
    float l = __fsub_rn(pl[i], minL[b]);
    float z = __fmul_rn(-20.0f, l);
    float ez = expf(z);
    float sg = __fdiv_rn(ez, __fadd_rn(1.0f, ez));
    float w2 = __fmul_rn(2.0f, sg);
    float wf = (w2 > 0.5f) ? 1.0f : 0.0f;
    weight[i] = wf;
    outW[i] = wf;
    outC[i] = (float)ci;
}

// ---------------------------------------------------------------------------
// K6: per-batch Procrustes reductions (double, shuffle-based)
// ---------------------------------------------------------------------------
__global__ __launch_bounds__(256) void proc_reduce(const float* __restrict__ srcP,
                                                   const float* __restrict__ tgtP,
                                                   const int* __restrict__ corres,
                                                   const float* __restrict__ weight,
                                                   double* __restrict__ red) {
    int b = blockIdx.x, tid = threadIdx.x;
    int w = tid >> 6, lane = tid & 63;
    __shared__ double sd[4][9];
    const float* xs = srcP + (size_t)b * 3 * NN;
    const float* ts = tgtP + (size_t)b * 3 * NN;
    const int* cr = corres + b * NN;
    const float* wv = weight + b * NN;

    double acc7[7] = {0, 0, 0, 0, 0, 0, 0};
    for (int nn2 = tid; nn2 < NN; nn2 += 256) {
        if (wv[nn2] != 0.0f) {
            acc7[0] += 1.0;
            acc7[1] += (double)xs[nn2];
            acc7[2] += (double)xs[NN + nn2];
            acc7[3] += (double)xs[2 * NN + nn2];
            int m = cr[nn2];
            acc7[4] += (double)ts[m];
            acc7[5] += (double)ts[NN + m];
            acc7[6] += (double)ts[2 * NN + m];
        }
    }
#pragma unroll
    for (int q = 0; q < 7; q++) {
        double r = wave_red_sum_d(acc7[q]);
        if (lane == 0) sd[w][q] = r;
    }
    __syncthreads();
    double tot7[7];
#pragma unroll
    for (int q = 0; q < 7; q++) tot7[q] = sd[0][q] + sd[1][q] + sd[2][q] + sd[3][q];
    __syncthreads();

    double W1e = tot7[0] + 1e-7;
    double mux0 = tot7[1] / W1e, mux1 = tot7[2] / W1e, mux2 = tot7[3] / W1e;
    double muy0 = tot7[4] / W1e, muy1 = tot7[5] / W1e, muy2 = tot7[6] / W1e;

    double s[9] = {0, 0, 0, 0, 0, 0, 0, 0, 0};
    for (int nn2 = tid; nn2 < NN; nn2 += 256) {
        if (wv[nn2] != 0.0f) {
            double dx0 = (double)xs[nn2] - mux0;
            double dx1 = (double)xs[NN + nn2] - mux1;
            double dx2 = (double)xs[2 * NN + nn2] - mux2;
            int m = cr[nn2];
            double dy0 = (double)ts[m] - muy0;
            double dy1 = (double)ts[NN + m] - muy1;
            double dy2 = (double)ts[2 * NN + m] - muy2;
            s[0] += dy0 * dx0; s[1] += dy0 * dx1; s[2] += dy0 * dx2;
            s[3] += dy1 * dx0; s[4] += dy1 * dx1; s[5] += dy1 * dx2;
            s[6] += dy2 * dx0; s[7] += dy2 * dx1; s[8] += dy2 * dx2;
        }
    }
#pragma unroll
    for (int q = 0; q < 9; q++) {
        double r = wave_red_sum_d(s[q]);
        if (lane == 0) sd[w][q] = r;
    }
    __syncthreads();
    if (tid < 9) {
        double tot = sd[0][tid] + sd[1][tid] + sd[2][tid] + sd[3][tid];
        red[b * 16 + tid] = tot / W1e;
    }
    if (tid == 9) {
        red[b * 16 + 9] = mux0; red[b * 16 + 10] = mux1; red[b * 16 + 11] = mux2;
        red[b * 16 + 12] = muy0; red[b * 16 + 13] = muy1; red[b * 16 + 14] = muy2;
        red[b * 16 + 15] = W1e;
    }
}

// ---------------------------------------------------------------------------
// K7: 3x3 SVD (one-sided Jacobi, f64) -> R, T
// ---------------------------------------------------------------------------
__device__ double det3(const double M[3][3]) {
    return M[0][0] * (M[1][1] * M[2][2] - M[1][2] * M[2][1]) -
           M[0][1] * (M[1][0] * M[2][2] - M[1][2] * M[2][0]) +
           M[0][2] * (M[1][0] * M[2][1] - M[1][1] * M[2][0]);
}

__global__ void svd_finalize(const double* __restrict__ red,
                             float* __restrict__ outR,
                             float* __restrict__ outT) {
    int b = threadIdx.x;
    if (b >= NBATCH) return;
    double A[3][3], Bm[3][3], V[3][3];
    for (int r = 0; r < 3; r++)
        for (int c2 = 0; c2 < 3; c2++) {
            A[r][c2] = red[b * 16 + r * 3 + c2];
            Bm[r][c2] = A[r][c2];
            V[r][c2] = (r == c2) ? 1.0 : 0.0;
        }
    double nrm2 = 0;
    for (int r = 0; r < 3; r++)
        for (int c2 = 0; c2 < 3; c2++) nrm2 += Bm[r][c2] * Bm[r][c2];

    for (int sweep = 0; sweep < 60; sweep++) {
        double off = 0;
        for (int p = 0; p < 2; p++) {
            for (int q = p + 1; q < 3; q++) {
                double al = 0, be = 0, ga = 0;
                for (int i = 0; i < 3; i++) {
                    al += Bm[i][p] * Bm[i][p];
                    be += Bm[i][q] * Bm[i][q];
                    ga += Bm[i][p] * Bm[i][q];
                }
                off += ga * ga;
                if (fabs(ga) > 1e-300) {
                    double ze = (be - al) / (2.0 * ga);
                    double t = copysign(1.0, ze) / (fabs(ze) + sqrt(1.0 + ze * ze));
                    double c = 1.0 / sqrt(1.0 + t * t), sn = c * t;
                    for (int i = 0; i < 3; i++) {
                        double bp = Bm[i][p], bq = Bm[i][q];
                        Bm[i][p] = c * bp - sn * bq;
                        Bm[i][q] = sn * bp + c * bq;
                        double vp = V[i][p], vq = V[i][q];
                        V[i][p] = c * vp - sn * vq;
                        V[i][q] = sn * vp + c * vq;
                    }
                }
            }
        }
        if (off <= 1e-30 * nrm2 * nrm2) break;
    }
    double sig[3];
    for (int j = 0; j < 3; j++) {
        double ss = 0;
        for (int i = 0; i < 3; i++) ss += Bm[i][j] * Bm[i][j];
        sig[j] = sqrt(ss);
    }
    for (int a = 0; a < 2; a++)
        for (int j = 0; j < 2 - a; j++)
            if (sig[j] < sig[j + 1]) {
                double t = sig[j]; sig[j] = sig[j + 1]; sig[j + 1] = t;
                for (int i = 0; i < 3; i++) {
                    double tb = Bm[i][j]; Bm[i][j] = Bm[i][j + 1]; Bm[i][j + 1] = tb;
                    double tv = V[i][j]; V[i][j] = V[i][j + 1]; V[i][j + 1] = tv;
                }
            }
    double U[3][3];
    for (int j = 0; j < 3; j++) {
        double inv = (sig[j] > 1e-150) ? 1.0 / sig[j] : 0.0;
        for (int i = 0; i < 3; i++) U[i][j] = Bm[i][j] * inv;
    }
    if (sig[2] <= 1e-10 * (sig[0] + 1e-300)) {
        double u0 = U[1][0] * U[2][1] - U[2][0] * U[1][1];
        double u1 = U[2][0] * U[0][1] - U[0][0] * U[2][1];
        double u2 = U[0][0] * U[1][1] - U[1][0] * U[0][1];
        double nr = sqrt(u0 * u0 + u1 * u1 + u2 * u2);
        if (nr > 1e-150) { U[0][2] = u0 / nr; U[1][2] = u1 / nr; U[2][2] = u2 / nr; }
    }
    double dU = det3(U), dV = det3(V);
    double s3 = (dU * dV >= 0.0) ? 1.0 : -1.0;
    double R[3][3];
    for (int i = 0; i < 3; i++)
        for (int j = 0; j < 3; j++)
            R[i][j] = U[i][0] * V[j][0] + U[i][1] * V[j][1] + s3 * U[i][2] * V[j][2];
    double mux[3] = {red[b * 16 + 9], red[b * 16 + 10], red[b * 16 + 11]};
    double muy[3] = {red[b * 16 + 12], red[b * 16 + 13], red[b * 16 + 14]};
    for (int i = 0; i < 3; i++) {
        for (int j = 0; j < 3; j++) outR[b * 9 + i * 3 + j] = (float)R[i][j];
        double t = muy[i] - (R[i][0] * mux[0] + R[i][1] * mux[1] + R[i][2] * mux[2]);
        outT[b * 3 + i] = (float)t;
    }
}

// ---------------------------------------------------------------------------
// host launcher
// ---------------------------------------------------------------------------
extern "C" void kernel_launch(void* const* d_in, const int* in_sizes, int n_in,
                              void* d_out, int out_size, void* d_ws, size_t ws_size,
                              hipStream_t stream) {
    const float* srcE = (const float*)d_in[0];
    const float* tgtE = (const float*)d_in[1];
    const float* srcP = (const float*)d_in[2];
    const float* tgtP = (const float*)d_in[3];
    float* out = (float*)d_out;  // R[36] T[12] corres[8192] weight[8192]

    char* w = (char*)d_ws;
    size_t off = 0;
    auto alloc = [&](size_t bytes) -> void* {
        void* p = w + off;
        off = (off + bytes + 255) & ~(size_t)255;
        return p;
    };
    float* corrTgt = (float*)alloc((size_t)NBATCH * NN * 3 * 4);
    int* corres = (int*)alloc((size_t)NBATCH * NN * 4);
    int* flags = (int*)alloc((size_t)NBATCH * NN * 4);
    unsigned long long* keys = (unsigned long long*)alloc((size_t)NBATCH * NN * 8);
    float* pointLoss = (float*)alloc((size_t)NBATCH * NN * 4);
    float* minL = (float*)alloc(NBATCH * 4);
    float* weight = (float*)alloc((size_t)NBATCH * NN * 4);
    double* red = (double*)alloc(NBATCH * 16 * 8);
    size_t fixed = off;
    int nb = (ws_size >= fixed + (size_t)NBATCH * NN * NN * 4) ? NBATCH : 1;
    float* scores = (float*)alloc((size_t)nb * NN * NN * 4);

    hipMemsetAsync(keys, 0, (size_t)NBATCH * NN * 8, stream);

    for (int b0 = 0; b0 < NBATCH; b0 += nb) {
        gemm_scores_mfma<<<dim3(NN / 128, NN / 128, nb), 256, 0, stream>>>(srcE, tgtE, scores, b0);
        row_softmax<<<dim3(NN / 4, nb), 256, 0, stream>>>(scores, tgtP, corrTgt, corres, flags, b0);
    }

    refine_argmax<<<dim3(NN / 256, NBATCH * NN), 256, 0, stream>>>(srcE, tgtE, flags, keys);
    gfm_kernel<<<dim3(NN / 4, NBATCH), 256, 0, stream>>>(srcP, corrTgt, pointLoss);
    min_kernel<<<NBATCH, 256, 0, stream>>>(pointLoss, minL);
    weight_kernel<<<(NBATCH * NN + 255) / 256, 256, 0, stream>>>(
        pointLoss, minL, corres, flags, keys, weight, out + 48, out + 48 + NBATCH * NN);
    proc_reduce<<<NBATCH, 256, 0, stream>>>(srcP, tgtP, corres, weight, red);
    svd_finalize<<<1, 64, 0, stream>>>(red, out, out + 36);
}